// Round 1
// baseline (2012.666 us; speedup 1.0000x reference)
//
#include <hip/hip_runtime.h>
#include <math.h>

#define NN 100000
#define NE 1600000
#define NG 64
#define FF 50
#define NL 3

// ---------------- degree ----------------
__global__ void k_deg(const int* __restrict__ dst, int* __restrict__ deg) {
  int e = blockIdx.x * blockDim.x + threadIdx.x;
  if (e < NE) atomicAdd(&deg[dst[e]], 1);
}

// ---------------- prefix scan (3 kernels) ----------------
__global__ void k_scan1(const int* __restrict__ deg, int* __restrict__ off, int* __restrict__ parts) {
  __shared__ int sm[1024];
  int i = blockIdx.x * 1024 + threadIdx.x;
  int v = (i < NN) ? deg[i] : 0;
  sm[threadIdx.x] = v;
  __syncthreads();
  for (int ofs = 1; ofs < 1024; ofs <<= 1) {
    int t = (threadIdx.x >= ofs) ? sm[threadIdx.x - ofs] : 0;
    __syncthreads();
    sm[threadIdx.x] += t;
    __syncthreads();
  }
  if (i < NN) off[i] = sm[threadIdx.x] - v;  // exclusive
  if (threadIdx.x == 1023) parts[blockIdx.x] = sm[1023];
}

__global__ void k_scan2(int* __restrict__ parts, int nb) {
  __shared__ int sm[128];
  int v = (threadIdx.x < nb) ? parts[threadIdx.x] : 0;
  sm[threadIdx.x] = v;
  __syncthreads();
  for (int ofs = 1; ofs < 128; ofs <<= 1) {
    int t = (threadIdx.x >= ofs) ? sm[threadIdx.x - ofs] : 0;
    __syncthreads();
    sm[threadIdx.x] += t;
    __syncthreads();
  }
  if (threadIdx.x < nb) parts[threadIdx.x] = sm[threadIdx.x] - v;  // exclusive
}

__global__ void k_scan3(int* __restrict__ off, const int* __restrict__ parts) {
  int i = blockIdx.x * 256 + threadIdx.x;
  if (i < NN) off[i] += parts[i >> 10];
  if (i == 0) off[NN] = NE;
}

// ---------------- node init: dinv, log1p(deg_c), sum log1p(deg) ----------------
__global__ void k_nodeinit(const int* __restrict__ deg, float* __restrict__ dinv,
                           float* __restrict__ lgc, float* __restrict__ scal) {
  int i = blockIdx.x * 256 + threadIdx.x;
  float lp = 0.f;
  if (i < NN) {
    int d = deg[i];
    dinv[i] = rsqrtf((float)(d + 1));
    int dc = d > 1 ? d : 1;
    lgc[i] = log1pf((float)dc);
    lp = log1pf((float)d);
  }
  for (int o = 32; o > 0; o >>= 1) lp += __shfl_down(lp, o);
  __shared__ float red[4];
  int lane = threadIdx.x & 63, w = threadIdx.x >> 6;
  if (lane == 0) red[w] = lp;
  __syncthreads();
  if (threadIdx.x == 0) atomicAdd(scal, red[0] + red[1] + red[2] + red[3]);
}

// ---------------- scatter (counting sort by dst) ----------------
__global__ void k_scatter(const int* __restrict__ src, const int* __restrict__ dst,
                          const int* __restrict__ off, int* __restrict__ cur, int* __restrict__ ssrc) {
  int e = blockIdx.x * blockDim.x + threadIdx.x;
  if (e < NE) {
    int d = dst[e];
    int p = off[d] + atomicAdd(&cur[d], 1);
    ssrc[p] = src[e];
  }
}

// ---------------- fuse post_W @ lin_W ----------------
__global__ void k_fusew(const float* __restrict__ postW, const float* __restrict__ postb,
                        const float* __restrict__ linW, const float* __restrict__ linb,
                        float* __restrict__ A, float* __restrict__ bias2) {
  int wid = (blockIdx.x * blockDim.x + threadIdx.x) >> 6;
  int f = threadIdx.x & 63;
  if (wid >= 3 * 651) return;
  int l = wid / 651, r = wid % 651;
  int fc = f < FF ? f : FF - 1;
  const float* lw = linW + l * FF * FF;
  float acc = 0.f;
  if (r < 650) {
    const float* pw = postW + (l * 650 + r) * FF;
    for (int j = 0; j < FF; ++j) acc += pw[j] * lw[j * FF + fc];
    if (f < FF) A[(l * 650 + r) * FF + f] = acc;
  } else {
    const float* pb = postb + l * FF;
    for (int j = 0; j < FF; ++j) acc += pb[j] * lw[j * FF + fc];
    if (f < FF) bias2[l * 64 + f] = acc + linb[l * FF + f];
  }
}

// ---------------- GCN: p = (x @ W_gcn) * dinv ----------------
__global__ void k_gcnpre(const float* __restrict__ x, const float* __restrict__ Wg,
                         const float* __restrict__ dinv, float* __restrict__ p) {
  int t = blockIdx.x * 256 + threadIdx.x;
  int n = t >> 6, f = t & 63;
  if (n >= NN || f >= FF) return;
  p[n * FF + f] = (x[2 * n] * Wg[f] + x[2 * n + 1] * Wg[FF + f]) * dinv[n];
}

// ---------------- GCN aggregation (wave per node) ----------------
__global__ void k_gcnagg(const float* __restrict__ p, const int* __restrict__ off,
                         const int* __restrict__ ssrc, const float* __restrict__ dinv,
                         const float* __restrict__ bg, float* __restrict__ h) {
  int wid = (blockIdx.x * blockDim.x + threadIdx.x) >> 6;
  int lane = threadIdx.x & 63;
  if (wid >= NN) return;
  int n = wid;
  int fc = lane < FF ? lane : FF - 1;
  float acc = p[n * FF + fc];  // self-loop term
  int lo = off[n], hi = off[n + 1];
  for (int base = lo; base < hi; base += 64) {
    int cnt = hi - base; if (cnt > 64) cnt = 64;
    int sidx = (base + lane < hi) ? ssrc[base + lane] : 0;
    for (int j = 0; j < cnt; ++j) {
      int s = __shfl(sidx, j);
      acc += p[s * FF + fc];
    }
  }
  if (lane < FF) h[n * FF + lane] = dinv[n] * acc + bg[lane];
}

// ---------------- PNA pre: c = h@WpT + bp, b = h@WpB (weights in VGPRs) ----------------
__global__ __launch_bounds__(256) void k_pre(const float* __restrict__ h, const float* __restrict__ preW,
                                             const float* __restrict__ preb, float* __restrict__ cb,
                                             float* __restrict__ bb, int l) {
  int lane = threadIdx.x & 63;
  int fc = lane < FF ? lane : FF - 1;
  bool act = lane < FF;
  const float* WT = preW + l * 100 * FF;
  const float* WB = WT + FF * FF;
  float wT[FF], wB[FF];
#pragma unroll
  for (int k = 0; k < FF; ++k) { wT[k] = WT[k * FF + fc]; wB[k] = WB[k * FF + fc]; }
  float bp = preb[l * FF + fc];
  int nwaves = (gridDim.x * blockDim.x) >> 6;
  int wid = (blockIdx.x * blockDim.x + threadIdx.x) >> 6;
  for (int n = wid; n < NN; n += nwaves) {
    float hv = h[n * FF + fc];
    float ca = 0.f, ba = 0.f;
#pragma unroll
    for (int k = 0; k < FF; ++k) {
      float hk = __shfl(hv, k);
      ca += hk * wT[k];
      ba += hk * wB[k];
    }
    if (act) { cb[n * FF + lane] = ca + bp; bb[n * FF + lane] = ba; }
  }
}

// ---------------- PNA aggregation (wave per node) ----------------
__global__ void k_agg(const float* __restrict__ bb, const float* __restrict__ cb,
                      const int* __restrict__ off, const int* __restrict__ ssrc,
                      const float* __restrict__ lgc, const float* __restrict__ scal,
                      float* __restrict__ aggb) {
  int wid = (blockIdx.x * blockDim.x + threadIdx.x) >> 6;
  int lane = threadIdx.x & 63;
  if (wid >= NN) return;
  int n = wid;
  int fc = lane < FF ? lane : FF - 1;
  float S = 0.f, S2 = 0.f, MN = INFINITY, MX = -INFINITY;
  int lo = off[n], hi = off[n + 1];
  for (int base = lo; base < hi; base += 64) {
    int cnt = hi - base; if (cnt > 64) cnt = 64;
    int sidx = (base + lane < hi) ? ssrc[base + lane] : 0;
    for (int j = 0; j < cnt; ++j) {
      int s = __shfl(sidx, j);
      float v = bb[s * FF + fc];
      S += v; S2 += v * v;
      MN = fminf(MN, v); MX = fmaxf(MX, v);
    }
  }
  int d = hi - lo;
  float mean, mnv, mxv, stdv;
  if (d > 0) {
    float inv = 1.f / (float)d;
    float m = S * inv;
    float var = S2 * inv - m * m; var = var > 0.f ? var : 0.f;
    stdv = sqrtf(var + 1e-5f);
    float c = cb[n * FF + fc];
    mean = c + m; mnv = c + MN; mxv = c + MX;
  } else {
    mean = 0.f; mnv = 0.f; mxv = 0.f; stdv = sqrtf(1e-5f);
  }
  float* row = aggb + (size_t)n * 208;
  if (lane < FF) {
    row[lane] = mean; row[50 + lane] = mnv; row[100 + lane] = mxv; row[150 + lane] = stdv;
  }
  if (lane == 50) {
    float avg = scal[0] * (1.f / NN);
    float lg = lgc[n];
    row[200] = lg / avg; row[201] = avg / lg;
  }
}

// ---------------- post GEMM: hout = [h|agg|amp*agg|att*agg](650) @ A + bias2 ----------------
__global__ __launch_bounds__(256) void k_gemm(const float* __restrict__ h, const float* __restrict__ aggb,
                                              const float* __restrict__ A, const float* __restrict__ bias2,
                                              float* __restrict__ out) {
  __shared__ __align__(16) float Xs[FF][68];  // [k][node], padded
  __shared__ __align__(16) float Ws[FF][64];  // [k][f'], padded
  int tid = threadIdx.x;
  int n0 = blockIdx.x * 64;
  int tn4 = tid & 15, tm4 = tid >> 4;  // cols 4*tn4.. , nodes 4*tm4..
  int g = tid >> 6;                    // wave id (loader group)
  int kk = tid & 63;                   // loader lane
  float acc[4][4] = {{0.f}};
  for (int c = 0; c < 13; ++c) {
    __syncthreads();
    // weights
    for (int k = g; k < FF; k += 4)
      if (kk < FF) Ws[k][kk] = A[(c * FF + k) * FF + kk];
    // X tile (transposed), with on-the-fly amp/att expansion
    if (kk < FF) {
      for (int r = 0; r < 16; ++r) {
        int n = n0 + g * 16 + r;
        float v = 0.f;
        if (n < NN) {
          const float* row = aggb + (size_t)n * 208;
          if (c == 0)      v = h[n * FF + kk];
          else if (c < 5)  v = row[(c - 1) * FF + kk];
          else if (c < 9)  v = row[(c - 5) * FF + kk] * row[200];
          else             v = row[(c - 9) * FF + kk] * row[201];
        }
        Xs[kk][g * 16 + r] = v;
      }
    }
    __syncthreads();
#pragma unroll 2
    for (int k = 0; k < FF; ++k) {
      float4 wv = *(const float4*)&Ws[k][tn4 * 4];
      float4 xv = *(const float4*)&Xs[k][tm4 * 4];
      acc[0][0] += xv.x * wv.x; acc[0][1] += xv.x * wv.y; acc[0][2] += xv.x * wv.z; acc[0][3] += xv.x * wv.w;
      acc[1][0] += xv.y * wv.x; acc[1][1] += xv.y * wv.y; acc[1][2] += xv.y * wv.z; acc[1][3] += xv.y * wv.w;
      acc[2][0] += xv.z * wv.x; acc[2][1] += xv.z * wv.y; acc[2][2] += xv.z * wv.z; acc[2][3] += xv.z * wv.w;
      acc[3][0] += xv.w * wv.x; acc[3][1] += xv.w * wv.y; acc[3][2] += xv.w * wv.z; acc[3][3] += xv.w * wv.w;
    }
  }
  for (int i = 0; i < 4; ++i) {
    int n = n0 + tm4 * 4 + i;
    if (n >= NN) continue;
    for (int j = 0; j < 4; ++j) {
      int f = tn4 * 4 + j;
      if (f < FF) out[n * FF + f] = acc[i][j] + bias2[f];
    }
  }
}

// ---------------- BN stats ----------------
__global__ void k_bnred(const float* __restrict__ h, float* __restrict__ bnsum) {
  int lane = threadIdx.x & 63, w = threadIdx.x >> 6;
  int wid = (blockIdx.x * blockDim.x + threadIdx.x) >> 6;
  int nw = (gridDim.x * blockDim.x) >> 6;
  int fc = lane < FF ? lane : FF - 1;
  float s = 0.f, q = 0.f;
  for (int n = wid; n < NN; n += nw) {
    float v = h[n * FF + fc];
    s += v; q += v * v;
  }
  __shared__ float sm[2][4][64];
  sm[0][w][lane] = (lane < FF) ? s : 0.f;
  sm[1][w][lane] = (lane < FF) ? q : 0.f;
  __syncthreads();
  if (w == 0 && lane < FF) {
    float ts = sm[0][0][lane] + sm[0][1][lane] + sm[0][2][lane] + sm[0][3][lane];
    float tq = sm[1][0][lane] + sm[1][1][lane] + sm[1][2][lane] + sm[1][3][lane];
    atomicAdd(&bnsum[lane], ts);
    atomicAdd(&bnsum[64 + lane], tq);
  }
}

// ---------------- BN normalize + relu (in place) ----------------
__global__ void k_bnnorm(float* __restrict__ h, const float* __restrict__ bnsum,
                         const float* __restrict__ gamma, const float* __restrict__ beta, int l) {
  int t = blockIdx.x * 256 + threadIdx.x;
  int n = t >> 6, f = t & 63;
  if (n >= NN || f >= FF) return;
  float mu = bnsum[f] * (1.f / NN);
  float vq = bnsum[64 + f] * (1.f / NN) - mu * mu;
  float rs = rsqrtf((vq > 0.f ? vq : 0.f) + 1e-5f);
  float a = rs * gamma[l * FF + f];
  float b = beta[l * FF + f] - mu * a;
  float v = h[n * FF + f] * a + b;
  h[n * FF + f] = v > 0.f ? v : 0.f;
}

// ---------------- graph readout + MLP ----------------
__global__ void k_readout(const float* __restrict__ h, const int* __restrict__ batch,
                          const float* __restrict__ W1, const float* __restrict__ b1,
                          const float* __restrict__ W2, const float* __restrict__ b2,
                          float* __restrict__ out) {
  int g = blockIdx.x;
  __shared__ int bounds[2];
  __shared__ float gv[64];
  __shared__ float red[4][64];
  if (threadIdx.x == 0) {
    int lo = 0, hi = NN;
    while (lo < hi) { int m = (lo + hi) >> 1; if (batch[m] < g) lo = m + 1; else hi = m; }
    bounds[0] = lo;
    int lo2 = lo, hi2 = NN;
    while (lo2 < hi2) { int m = (lo2 + hi2) >> 1; if (batch[m] < g + 1) lo2 = m + 1; else hi2 = m; }
    bounds[1] = lo2;
  }
  __syncthreads();
  int lo = bounds[0], hi = bounds[1];
  int lane = threadIdx.x & 63, w = threadIdx.x >> 6;
  int fc = lane < FF ? lane : FF - 1;
  float acc = 0.f;
  for (int n = lo + w; n < hi; n += 4) acc += h[n * FF + fc];
  red[w][lane] = (lane < FF) ? acc : 0.f;
  __syncthreads();
  if (w == 0) gv[lane] = red[0][lane] + red[1][lane] + red[2][lane] + red[3][lane];
  __syncthreads();
  if (threadIdx.x < 64) {
    int j = threadIdx.x;
    float hj = 0.f;
    if (j < 25) {
      float a = b1[j];
      for (int f = 0; f < FF; ++f) a += gv[f] * W1[f * 25 + j];
      hj = (a > 0.f ? a : 0.f) * W2[j];
    }
    for (int o = 32; o > 0; o >>= 1) hj += __shfl_down(hj, o);
    if (j == 0) out[g] = hj + b2[0];
  }
}

extern "C" void kernel_launch(void* const* d_in, const int* in_sizes, int n_in,
                              void* d_out, int out_size, void* d_ws, size_t ws_size,
                              hipStream_t stream) {
  const float* x     = (const float*)d_in[0];
  const int*   ei    = (const int*)d_in[1];
  const int*   src   = ei;
  const int*   dst   = ei + NE;
  const int*   batch = (const int*)d_in[2];
  const float* Wg    = (const float*)d_in[3];
  const float* bg    = (const float*)d_in[4];
  const float* preW  = (const float*)d_in[5];
  const float* preb  = (const float*)d_in[6];
  const float* postW = (const float*)d_in[7];
  const float* postb = (const float*)d_in[8];
  const float* linW  = (const float*)d_in[9];
  const float* linb  = (const float*)d_in[10];
  const float* gamma = (const float*)d_in[11];
  const float* beta  = (const float*)d_in[12];
  const float* W1    = (const float*)d_in[13];
  const float* b1    = (const float*)d_in[14];
  const float* W2    = (const float*)d_in[15];
  const float* b2    = (const float*)d_in[16];
  float* out = (float*)d_out;

  char* W = (char*)d_ws;
  int*   deg   = (int*)(W + 0);          // 400384
  int*   cur   = (int*)(W + 400384);     // 400384
  int*   off   = (int*)(W + 800768);     // 400896
  int*   ssrc  = (int*)(W + 1201664);    // 6400000
  int*   parts = (int*)(W + 7601664);    // 4096
  float* dinv  = (float*)(W + 7605760);  // 400384
  float* lgc   = (float*)(W + 8006144);  // 400384
  float* scal  = (float*)(W + 8406528);  // 512
  float* bnsum = (float*)(W + 8407040);  // 2048 (3 layers x 128 floats)
  float* Af    = (float*)(W + 8409088);  // 390144
  float* bias2 = (float*)(W + 8799232);  // 1024
  float* h0    = (float*)(W + 8800256);  // 20000256
  float* h1    = (float*)(W + 28800512); // 20000256
  float* cb    = (float*)(W + 48800768); // 20000256
  float* bbf   = (float*)(W + 68801024); // 20000256
  float* aggb  = (float*)(W + 88801280); // 83200000   (total ~172 MB)

  hipMemsetAsync(deg, 0, 800768, stream);   // deg + cur
  hipMemsetAsync(scal, 0, 2560, stream);    // scal + bnsum

  k_deg<<<(NE + 255) / 256, 256, 0, stream>>>(dst, deg);
  k_scan1<<<98, 1024, 0, stream>>>(deg, off, parts);
  k_scan2<<<1, 128, 0, stream>>>(parts, 98);
  k_scan3<<<(NN + 255) / 256, 256, 0, stream>>>(off, parts);
  k_nodeinit<<<(NN + 255) / 256, 256, 0, stream>>>(deg, dinv, lgc, scal);
  k_scatter<<<(NE + 255) / 256, 256, 0, stream>>>(src, dst, off, cur, ssrc);
  k_fusew<<<(3 * 651 + 3) / 4, 256, 0, stream>>>(postW, postb, linW, linb, Af, bias2);

  k_gcnpre<<<NN / 4, 256, 0, stream>>>(x, Wg, dinv, cb);
  k_gcnagg<<<NN / 4, 256, 0, stream>>>(cb, off, ssrc, dinv, bg, h0);

  float* hin = h0;
  float* hout = h1;
  for (int l = 0; l < NL; ++l) {
    k_pre<<<1024, 256, 0, stream>>>(hin, preW, preb, cb, bbf, l);
    k_agg<<<NN / 4, 256, 0, stream>>>(bbf, cb, off, ssrc, lgc, scal, aggb);
    k_gemm<<<(NN + 63) / 64, 256, 0, stream>>>(hin, aggb, Af + l * 650 * FF, bias2 + l * 64, hout);
    k_bnred<<<256, 256, 0, stream>>>(hout, bnsum + l * 128);
    k_bnnorm<<<NN / 4, 256, 0, stream>>>(hout, bnsum + l * 128, gamma, beta, l);
    float* t = hin; hin = hout; hout = t;
  }
  k_readout<<<NG, 256, 0, stream>>>(hin, batch, W1, b1, W2, b2, out);
}

// Round 2
// 1674.717 us; speedup vs baseline: 1.2018x; 1.2018x over previous
//
#include <hip/hip_runtime.h>
#include <math.h>

#define NN 100000
#define NE 1600000
#define NG 64
#define FF 50
#define NL 3

typedef short bf16x8 __attribute__((ext_vector_type(8)));
typedef float f32x4 __attribute__((ext_vector_type(4)));

__device__ __forceinline__ short f2bf(float f) {
  return __builtin_bit_cast(short, (__bf16)f);
}

// ---------------- degree ----------------
__global__ void k_deg(const int* __restrict__ dst, int* __restrict__ deg) {
  int e = blockIdx.x * blockDim.x + threadIdx.x;
  if (e < NE) atomicAdd(&deg[dst[e]], 1);
}

// ---------------- prefix scan (3 kernels) ----------------
__global__ void k_scan1(const int* __restrict__ deg, int* __restrict__ off, int* __restrict__ parts) {
  __shared__ int sm[1024];
  int i = blockIdx.x * 1024 + threadIdx.x;
  int v = (i < NN) ? deg[i] : 0;
  sm[threadIdx.x] = v;
  __syncthreads();
  for (int ofs = 1; ofs < 1024; ofs <<= 1) {
    int t = (threadIdx.x >= ofs) ? sm[threadIdx.x - ofs] : 0;
    __syncthreads();
    sm[threadIdx.x] += t;
    __syncthreads();
  }
  if (i < NN) off[i] = sm[threadIdx.x] - v;  // exclusive
  if (threadIdx.x == 1023) parts[blockIdx.x] = sm[1023];
}

__global__ void k_scan2(int* __restrict__ parts, int nb) {
  __shared__ int sm[128];
  int v = (threadIdx.x < nb) ? parts[threadIdx.x] : 0;
  sm[threadIdx.x] = v;
  __syncthreads();
  for (int ofs = 1; ofs < 128; ofs <<= 1) {
    int t = (threadIdx.x >= ofs) ? sm[threadIdx.x - ofs] : 0;
    __syncthreads();
    sm[threadIdx.x] += t;
    __syncthreads();
  }
  if (threadIdx.x < nb) parts[threadIdx.x] = sm[threadIdx.x] - v;  // exclusive
}

__global__ void k_scan3(int* __restrict__ off, const int* __restrict__ parts) {
  int i = blockIdx.x * 256 + threadIdx.x;
  if (i < NN) off[i] += parts[i >> 10];
  if (i == 0) off[NN] = NE;
}

// ---------------- node init ----------------
__global__ void k_nodeinit(const int* __restrict__ deg, float* __restrict__ dinv,
                           float* __restrict__ lgc, float* __restrict__ scal) {
  int i = blockIdx.x * 256 + threadIdx.x;
  float lp = 0.f;
  if (i < NN) {
    int d = deg[i];
    dinv[i] = rsqrtf((float)(d + 1));
    int dc = d > 1 ? d : 1;
    lgc[i] = log1pf((float)dc);
    lp = log1pf((float)d);
  }
  for (int o = 32; o > 0; o >>= 1) lp += __shfl_down(lp, o);
  __shared__ float red[4];
  int lane = threadIdx.x & 63, w = threadIdx.x >> 6;
  if (lane == 0) red[w] = lp;
  __syncthreads();
  if (threadIdx.x == 0) atomicAdd(scal, red[0] + red[1] + red[2] + red[3]);
}

// ---------------- scatter (counting sort by dst) ----------------
__global__ void k_scatter(const int* __restrict__ src, const int* __restrict__ dst,
                          const int* __restrict__ off, int* __restrict__ cur, int* __restrict__ ssrc) {
  int e = blockIdx.x * blockDim.x + threadIdx.x;
  if (e < NE) {
    int d = dst[e];
    int p = off[d] + atomicAdd(&cur[d], 1);
    ssrc[p] = src[e];
  }
}

// ---------------- fuse post_W @ lin_W ----------------
__global__ void k_fusew(const float* __restrict__ postW, const float* __restrict__ postb,
                        const float* __restrict__ linW, const float* __restrict__ linb,
                        float* __restrict__ A, float* __restrict__ bias2) {
  int wid = (blockIdx.x * blockDim.x + threadIdx.x) >> 6;
  int f = threadIdx.x & 63;
  if (wid >= 3 * 651) return;
  int l = wid / 651, r = wid % 651;
  int fc = f < FF ? f : FF - 1;
  const float* lw = linW + l * FF * FF;
  float acc = 0.f;
  if (r < 650) {
    const float* pw = postW + (l * 650 + r) * FF;
    for (int j = 0; j < FF; ++j) acc += pw[j] * lw[j * FF + fc];
    if (f < FF) A[(l * 650 + r) * FF + f] = acc;
  } else {
    const float* pb = postb + l * FF;
    for (int j = 0; j < FF; ++j) acc += pb[j] * lw[j * FF + fc];
    if (f < FF) bias2[l * 64 + f] = acc + linb[l * FF + f];
  }
}

// ---------------- pack A into bf16 B-operand layout [l][c][col f][k 64] ----------------
__global__ void k_packA(const float* __restrict__ Af, short* __restrict__ Abt) {
  int t = blockIdx.x * 256 + threadIdx.x;
  if (t >= 3 * 13 * 64 * 64) return;
  int kk = t & 63;
  int f = (t >> 6) & 63;
  int lc = t >> 12;       // l*13 + c
  int c = lc % 13;
  int l = lc / 13;
  float v = 0.f;
  if (kk < FF && f < FF) v = Af[((size_t)(l * 650 + c * FF + kk)) * FF + f];
  Abt[t] = f2bf(v);
}

// ---------------- GCN: p = (x @ W_gcn) * dinv ----------------
__global__ void k_gcnpre(const float* __restrict__ x, const float* __restrict__ Wg,
                         const float* __restrict__ dinv, float* __restrict__ p) {
  int t = blockIdx.x * 256 + threadIdx.x;
  int n = t >> 6, f = t & 63;
  if (n >= NN || f >= FF) return;
  p[n * FF + f] = (x[2 * n] * Wg[f] + x[2 * n + 1] * Wg[FF + f]) * dinv[n];
}

// ---------------- GCN aggregation (wave per node) ----------------
__global__ void k_gcnagg(const float* __restrict__ p, const int* __restrict__ off,
                         const int* __restrict__ ssrc, const float* __restrict__ dinv,
                         const float* __restrict__ bg, float* __restrict__ h) {
  int wid = (blockIdx.x * blockDim.x + threadIdx.x) >> 6;
  int lane = threadIdx.x & 63;
  if (wid >= NN) return;
  int n = wid;
  int fc = lane < FF ? lane : FF - 1;
  float acc = p[n * FF + fc];  // self-loop term
  int lo = off[n], hi = off[n + 1];
  for (int base = lo; base < hi; base += 64) {
    int cnt = hi - base; if (cnt > 64) cnt = 64;
    int sidx = (base + lane < hi) ? ssrc[base + lane] : 0;
    for (int j = 0; j < cnt; ++j) {
      int s = __shfl(sidx, j);
      acc += p[s * FF + fc];
    }
  }
  if (lane < FF) h[n * FF + lane] = dinv[n] * acc + bg[lane];
}

// ---------------- PNA pre: c = h@WpT + bp, b = h@WpB ----------------
__global__ __launch_bounds__(256) void k_pre(const float* __restrict__ h, const float* __restrict__ preW,
                                             const float* __restrict__ preb, float* __restrict__ cb,
                                             float* __restrict__ bb, int l) {
  int lane = threadIdx.x & 63;
  int fc = lane < FF ? lane : FF - 1;
  bool act = lane < FF;
  const float* WT = preW + l * 100 * FF;
  const float* WB = WT + FF * FF;
  float wT[FF], wB[FF];
#pragma unroll
  for (int k = 0; k < FF; ++k) { wT[k] = WT[k * FF + fc]; wB[k] = WB[k * FF + fc]; }
  float bp = preb[l * FF + fc];
  int nwaves = (gridDim.x * blockDim.x) >> 6;
  int wid = (blockIdx.x * blockDim.x + threadIdx.x) >> 6;
  for (int n = wid; n < NN; n += nwaves) {
    float hv = h[n * FF + fc];
    float ca = 0.f, ba = 0.f;
#pragma unroll
    for (int k = 0; k < FF; ++k) {
      float hk = __shfl(hv, k);
      ca += hk * wT[k];
      ba += hk * wB[k];
    }
    if (act) { cb[n * FF + lane] = ca + bp; bb[n * FF + lane] = ba; }
  }
}

// ---------------- PNA aggregation (wave per node) ----------------
__global__ void k_agg(const float* __restrict__ bb, const float* __restrict__ cb,
                      const int* __restrict__ off, const int* __restrict__ ssrc,
                      const float* __restrict__ lgc, const float* __restrict__ scal,
                      float* __restrict__ aggb) {
  int wid = (blockIdx.x * blockDim.x + threadIdx.x) >> 6;
  int lane = threadIdx.x & 63;
  if (wid >= NN) return;
  int n = wid;
  int fc = lane < FF ? lane : FF - 1;
  float S = 0.f, S2 = 0.f, MN = INFINITY, MX = -INFINITY;
  int lo = off[n], hi = off[n + 1];
  for (int base = lo; base < hi; base += 64) {
    int cnt = hi - base; if (cnt > 64) cnt = 64;
    int sidx = (base + lane < hi) ? ssrc[base + lane] : 0;
    for (int j = 0; j < cnt; ++j) {
      int s = __shfl(sidx, j);
      float v = bb[s * FF + fc];
      S += v; S2 += v * v;
      MN = fminf(MN, v); MX = fmaxf(MX, v);
    }
  }
  int d = hi - lo;
  float mean, mnv, mxv, stdv;
  if (d > 0) {
    float inv = 1.f / (float)d;
    float m = S * inv;
    float var = S2 * inv - m * m; var = var > 0.f ? var : 0.f;
    stdv = sqrtf(var + 1e-5f);
    float c = cb[n * FF + fc];
    mean = c + m; mnv = c + MN; mxv = c + MX;
  } else {
    mean = 0.f; mnv = 0.f; mxv = 0.f; stdv = sqrtf(1e-5f);
  }
  float* row = aggb + (size_t)n * 208;
  if (lane < FF) {
    row[lane] = mean; row[50 + lane] = mnv; row[100 + lane] = mxv; row[150 + lane] = stdv;
  }
  if (lane == 50) {
    float avg = scal[0] * (1.f / NN);
    float lg = lgc[n];
    row[200] = lg / avg; row[201] = avg / lg;
  }
}

// ---------------- post GEMM (bf16 MFMA): out = X(650) @ A + bias2 ----------------
// X = [h | agg | agg*amp | agg*att], K padded to 13 chunks x 64.
// Per block: 128 nodes x 64 cols. Per wave: 32 nodes x 64 cols.
__global__ __launch_bounds__(256) void k_gemm(const float* __restrict__ h, const float* __restrict__ aggb,
                                              const short* __restrict__ Abt, const float* __restrict__ bias2,
                                              float* __restrict__ out) {
  __shared__ short Xs[128][72];  // [node][k], stride 72 => 16B-aligned rows, 2-way banks
  __shared__ short Bs[64][72];   // [col][k]
  int tid = threadIdx.x;
  int n0 = blockIdx.x * 128;
  int w = tid >> 6, lane = tid & 63;
  int q = lane >> 4, m16 = lane & 15;

  // X staging role: thread covers node nl for k-range [kh, kh+32)
  int nl = tid & 127;
  int kh = (tid >> 7) * 32;
  int n = n0 + nl;
  bool nvalid = n < NN;
  const float* arow = aggb + (size_t)(nvalid ? n : 0) * 208;
  float amp = 1.f, att = 1.f;
  if (nvalid) { amp = arow[200]; att = arow[201]; }
  const float* hrow = h + (size_t)(nvalid ? n : 0) * FF;

  // B staging role
  int bf = tid >> 2;            // col 0..63
  int bko = (tid & 3) * 16;     // k offset 0/16/32/48

  f32x4 acc[2][4];
#pragma unroll
  for (int i = 0; i < 2; ++i)
#pragma unroll
    for (int j = 0; j < 4; ++j) acc[i][j] = (f32x4){0.f, 0.f, 0.f, 0.f};

  for (int c = 0; c < 13; ++c) {
    if (c) __syncthreads();
    // --- stage B slice: Abt[c][f][k] 64x64 bf16 ---
    {
      const float4* g = (const float4*)(Abt + (c << 12) + (bf << 6) + bko);
      float4 v0 = g[0], v1 = g[1];
      *(float4*)&Bs[bf][bko] = v0;
      *(float4*)&Bs[bf][bko + 8] = v1;
    }
    // --- stage X: node nl, k in [kh, kh+32) ---
    {
      const float* srcp;
      float sc = 1.f;
      if (c == 0) srcp = hrow;
      else {
        int ci = c - 1;
        if (ci >= 8) { ci -= 8; sc = att; }
        else if (ci >= 4) { ci -= 4; sc = amp; }
        srcp = arow + ci * FF;
      }
#pragma unroll
      for (int j = 0; j < 32; j += 2) {
        int kk = kh + j;
        float2 v = {0.f, 0.f};
        if (nvalid && kk < FF) v = *(const float2*)(srcp + kk);
        Xs[nl][kk] = f2bf(v.x * sc);
        Xs[nl][kk + 1] = f2bf(v.y * sc);
      }
    }
    __syncthreads();
    // --- MFMA: two k-halves of 32 ---
#pragma unroll
    for (int half = 0; half < 2; ++half) {
      int ko = half * 32 + q * 8;
      bf16x8 a0 = *(const bf16x8*)&Xs[w * 32 + m16][ko];
      bf16x8 a1 = *(const bf16x8*)&Xs[w * 32 + 16 + m16][ko];
#pragma unroll
      for (int ft = 0; ft < 4; ++ft) {
        bf16x8 b = *(const bf16x8*)&Bs[ft * 16 + m16][ko];
        acc[0][ft] = __builtin_amdgcn_mfma_f32_16x16x32_bf16(a0, b, acc[0][ft], 0, 0, 0);
        acc[1][ft] = __builtin_amdgcn_mfma_f32_16x16x32_bf16(a1, b, acc[1][ft], 0, 0, 0);
      }
    }
  }
  // --- epilogue: D[row=q*4+r][col=m16] ---
#pragma unroll
  for (int mt = 0; mt < 2; ++mt) {
#pragma unroll
    for (int ft = 0; ft < 4; ++ft) {
      int col = ft * 16 + m16;
      if (col >= FF) continue;
      float bv = bias2[col];
#pragma unroll
      for (int r = 0; r < 4; ++r) {
        int node = n0 + w * 32 + mt * 16 + q * 4 + r;
        if (node < NN) out[node * FF + col] = acc[mt][ft][r] + bv;
      }
    }
  }
}

// ---------------- BN stats ----------------
__global__ void k_bnred(const float* __restrict__ h, float* __restrict__ bnsum) {
  int lane = threadIdx.x & 63, w = threadIdx.x >> 6;
  int wid = (blockIdx.x * blockDim.x + threadIdx.x) >> 6;
  int nw = (gridDim.x * blockDim.x) >> 6;
  int fc = lane < FF ? lane : FF - 1;
  float s = 0.f, q = 0.f;
  for (int n = wid; n < NN; n += nw) {
    float v = h[n * FF + fc];
    s += v; q += v * v;
  }
  __shared__ float sm[2][4][64];
  sm[0][w][lane] = (lane < FF) ? s : 0.f;
  sm[1][w][lane] = (lane < FF) ? q : 0.f;
  __syncthreads();
  if (w == 0 && lane < FF) {
    float ts = sm[0][0][lane] + sm[0][1][lane] + sm[0][2][lane] + sm[0][3][lane];
    float tq = sm[1][0][lane] + sm[1][1][lane] + sm[1][2][lane] + sm[1][3][lane];
    atomicAdd(&bnsum[lane], ts);
    atomicAdd(&bnsum[64 + lane], tq);
  }
}

// ---------------- BN normalize + relu (in place) ----------------
__global__ void k_bnnorm(float* __restrict__ h, const float* __restrict__ bnsum,
                         const float* __restrict__ gamma, const float* __restrict__ beta, int l) {
  int t = blockIdx.x * 256 + threadIdx.x;
  int n = t >> 6, f = t & 63;
  if (n >= NN || f >= FF) return;
  float mu = bnsum[f] * (1.f / NN);
  float vq = bnsum[64 + f] * (1.f / NN) - mu * mu;
  float rs = rsqrtf((vq > 0.f ? vq : 0.f) + 1e-5f);
  float a = rs * gamma[l * FF + f];
  float b = beta[l * FF + f] - mu * a;
  float v = h[n * FF + f] * a + b;
  h[n * FF + f] = v > 0.f ? v : 0.f;
}

// ---------------- graph readout + MLP ----------------
__global__ void k_readout(const float* __restrict__ h, const int* __restrict__ batch,
                          const float* __restrict__ W1, const float* __restrict__ b1,
                          const float* __restrict__ W2, const float* __restrict__ b2,
                          float* __restrict__ out) {
  int g = blockIdx.x;
  __shared__ int bounds[2];
  __shared__ float gv[64];
  __shared__ float red[4][64];
  if (threadIdx.x == 0) {
    int lo = 0, hi = NN;
    while (lo < hi) { int m = (lo + hi) >> 1; if (batch[m] < g) lo = m + 1; else hi = m; }
    bounds[0] = lo;
    int lo2 = lo, hi2 = NN;
    while (lo2 < hi2) { int m = (lo2 + hi2) >> 1; if (batch[m] < g + 1) lo2 = m + 1; else hi2 = m; }
    bounds[1] = lo2;
  }
  __syncthreads();
  int lo = bounds[0], hi = bounds[1];
  int lane = threadIdx.x & 63, w = threadIdx.x >> 6;
  int fc = lane < FF ? lane : FF - 1;
  float acc = 0.f;
  for (int n = lo + w; n < hi; n += 4) acc += h[n * FF + fc];
  red[w][lane] = (lane < FF) ? acc : 0.f;
  __syncthreads();
  if (w == 0) gv[lane] = red[0][lane] + red[1][lane] + red[2][lane] + red[3][lane];
  __syncthreads();
  if (threadIdx.x < 64) {
    int j = threadIdx.x;
    float hj = 0.f;
    if (j < 25) {
      float a = b1[j];
      for (int f = 0; f < FF; ++f) a += gv[f] * W1[f * 25 + j];
      hj = (a > 0.f ? a : 0.f) * W2[j];
    }
    for (int o = 32; o > 0; o >>= 1) hj += __shfl_down(hj, o);
    if (j == 0) out[g] = hj + b2[0];
  }
}

extern "C" void kernel_launch(void* const* d_in, const int* in_sizes, int n_in,
                              void* d_out, int out_size, void* d_ws, size_t ws_size,
                              hipStream_t stream) {
  const float* x     = (const float*)d_in[0];
  const int*   ei    = (const int*)d_in[1];
  const int*   src   = ei;
  const int*   dst   = ei + NE;
  const int*   batch = (const int*)d_in[2];
  const float* Wg    = (const float*)d_in[3];
  const float* bg    = (const float*)d_in[4];
  const float* preW  = (const float*)d_in[5];
  const float* preb  = (const float*)d_in[6];
  const float* postW = (const float*)d_in[7];
  const float* postb = (const float*)d_in[8];
  const float* linW  = (const float*)d_in[9];
  const float* linb  = (const float*)d_in[10];
  const float* gamma = (const float*)d_in[11];
  const float* beta  = (const float*)d_in[12];
  const float* W1    = (const float*)d_in[13];
  const float* b1    = (const float*)d_in[14];
  const float* W2    = (const float*)d_in[15];
  const float* b2    = (const float*)d_in[16];
  float* out = (float*)d_out;

  char* W = (char*)d_ws;
  int*   deg   = (int*)(W + 0);          // 400384
  int*   cur   = (int*)(W + 400384);     // 400384
  int*   off   = (int*)(W + 800768);     // 400896
  int*   ssrc  = (int*)(W + 1201664);    // 6400000
  int*   parts = (int*)(W + 7601664);    // 4096
  float* dinv  = (float*)(W + 7605760);  // 400384
  float* lgc   = (float*)(W + 8006144);  // 400384
  float* scal  = (float*)(W + 8406528);  // 512
  float* bnsum = (float*)(W + 8407040);  // 2048
  float* Af    = (float*)(W + 8409088);  // 390144
  float* bias2 = (float*)(W + 8799232);  // 1024
  float* h0    = (float*)(W + 8800256);  // 20000256
  float* h1    = (float*)(W + 28800512); // 20000256
  float* cb    = (float*)(W + 48800768); // 20000256
  float* bbf   = (float*)(W + 68801024); // 20000256
  float* aggb  = (float*)(W + 88801280); // 83200000
  short* Abt   = (short*)(W + 172001280);// 3*13*64*64*2 = 319488  (total ~172.3 MB)

  hipMemsetAsync(deg, 0, 800768, stream);   // deg + cur
  hipMemsetAsync(scal, 0, 2560, stream);    // scal + bnsum

  k_deg<<<(NE + 255) / 256, 256, 0, stream>>>(dst, deg);
  k_scan1<<<98, 1024, 0, stream>>>(deg, off, parts);
  k_scan2<<<1, 128, 0, stream>>>(parts, 98);
  k_scan3<<<(NN + 255) / 256, 256, 0, stream>>>(off, parts);
  k_nodeinit<<<(NN + 255) / 256, 256, 0, stream>>>(deg, dinv, lgc, scal);
  k_scatter<<<(NE + 255) / 256, 256, 0, stream>>>(src, dst, off, cur, ssrc);
  k_fusew<<<(3 * 651 + 3) / 4, 256, 0, stream>>>(postW, postb, linW, linb, Af, bias2);
  k_packA<<<(3 * 13 * 64 * 64 + 255) / 256, 256, 0, stream>>>(Af, Abt);

  k_gcnpre<<<NN / 4, 256, 0, stream>>>(x, Wg, dinv, cb);
  k_gcnagg<<<NN / 4, 256, 0, stream>>>(cb, off, ssrc, dinv, bg, h0);

  float* hin = h0;
  float* hout = h1;
  for (int l = 0; l < NL; ++l) {
    k_pre<<<1024, 256, 0, stream>>>(hin, preW, preb, cb, bbf, l);
    k_agg<<<NN / 4, 256, 0, stream>>>(bbf, cb, off, ssrc, lgc, scal, aggb);
    k_gemm<<<(NN + 127) / 128, 256, 0, stream>>>(hin, aggb, Abt + l * 13 * 64 * 64, bias2 + l * 64, hout);
    k_bnred<<<256, 256, 0, stream>>>(hout, bnsum + l * 128);
    k_bnnorm<<<NN / 4, 256, 0, stream>>>(hout, bnsum + l * 128, gamma, beta, l);
    float* t = hin; hin = hout; hout = t;
  }
  k_readout<<<NG, 256, 0, stream>>>(hin, batch, W1, b1, W2, b2, out);
}

// Round 3
// 1263.320 us; speedup vs baseline: 1.5932x; 1.3256x over previous
//
#include <hip/hip_runtime.h>
#include <math.h>

#define NN 100000
#define NE 1600000
#define NG 64
#define FF 50
#define NL 3

typedef short bf16x8 __attribute__((ext_vector_type(8)));
typedef float f32x4 __attribute__((ext_vector_type(4)));

__device__ __forceinline__ short f2bf(float f) {
  return __builtin_bit_cast(short, (__bf16)f);
}
__device__ __forceinline__ float bf2f(short s) {
  unsigned int u = ((unsigned int)(unsigned short)s) << 16;
  return __builtin_bit_cast(float, u);
}

// ---------------- degree ----------------
__global__ void k_deg(const int* __restrict__ dst, int* __restrict__ deg) {
  int e = blockIdx.x * blockDim.x + threadIdx.x;
  if (e < NE) atomicAdd(&deg[dst[e]], 1);
}

// ---------------- prefix scan ----------------
__global__ void k_scan1(const int* __restrict__ deg, int* __restrict__ off, int* __restrict__ parts) {
  __shared__ int sm[1024];
  int i = blockIdx.x * 1024 + threadIdx.x;
  int v = (i < NN) ? deg[i] : 0;
  sm[threadIdx.x] = v;
  __syncthreads();
  for (int ofs = 1; ofs < 1024; ofs <<= 1) {
    int t = (threadIdx.x >= ofs) ? sm[threadIdx.x - ofs] : 0;
    __syncthreads();
    sm[threadIdx.x] += t;
    __syncthreads();
  }
  if (i < NN) off[i] = sm[threadIdx.x] - v;
  if (threadIdx.x == 1023) parts[blockIdx.x] = sm[1023];
}

__global__ void k_scan2(int* __restrict__ parts, int nb) {
  __shared__ int sm[128];
  int v = (threadIdx.x < nb) ? parts[threadIdx.x] : 0;
  sm[threadIdx.x] = v;
  __syncthreads();
  for (int ofs = 1; ofs < 128; ofs <<= 1) {
    int t = (threadIdx.x >= ofs) ? sm[threadIdx.x - ofs] : 0;
    __syncthreads();
    sm[threadIdx.x] += t;
    __syncthreads();
  }
  if (threadIdx.x < nb) parts[threadIdx.x] = sm[threadIdx.x] - v;
}

__global__ void k_scan3(int* __restrict__ off, const int* __restrict__ parts) {
  int i = blockIdx.x * 256 + threadIdx.x;
  if (i < NN) off[i] += parts[i >> 10];
  if (i == 0) off[NN] = NE;
}

// ---------------- node init ----------------
__global__ void k_nodeinit(const int* __restrict__ deg, float* __restrict__ dinv,
                           float* __restrict__ lgc, float* __restrict__ scal) {
  int i = blockIdx.x * 256 + threadIdx.x;
  float lp = 0.f;
  if (i < NN) {
    int d = deg[i];
    dinv[i] = rsqrtf((float)(d + 1));
    int dc = d > 1 ? d : 1;
    lgc[i] = log1pf((float)dc);
    lp = log1pf((float)d);
  }
  for (int o = 32; o > 0; o >>= 1) lp += __shfl_down(lp, o);
  __shared__ float red[4];
  int lane = threadIdx.x & 63, w = threadIdx.x >> 6;
  if (lane == 0) red[w] = lp;
  __syncthreads();
  if (threadIdx.x == 0) atomicAdd(scal, red[0] + red[1] + red[2] + red[3]);
}

// ---------------- scatter ----------------
__global__ void k_scatter(const int* __restrict__ src, const int* __restrict__ dst,
                          const int* __restrict__ off, int* __restrict__ cur, int* __restrict__ ssrc) {
  int e = blockIdx.x * blockDim.x + threadIdx.x;
  if (e < NE) {
    int d = dst[e];
    int p = off[d] + atomicAdd(&cur[d], 1);
    ssrc[p] = src[e];
  }
}

// ---------------- fuse post_W @ lin_W ----------------
__global__ void k_fusew(const float* __restrict__ postW, const float* __restrict__ postb,
                        const float* __restrict__ linW, const float* __restrict__ linb,
                        float* __restrict__ A, float* __restrict__ bias2) {
  int wid = (blockIdx.x * blockDim.x + threadIdx.x) >> 6;
  int f = threadIdx.x & 63;
  if (wid >= 3 * 651) return;
  int l = wid / 651, r = wid % 651;
  int fc = f < FF ? f : FF - 1;
  const float* lw = linW + l * FF * FF;
  float acc = 0.f;
  if (r < 650) {
    const float* pw = postW + (l * 650 + r) * FF;
    for (int j = 0; j < FF; ++j) acc += pw[j] * lw[j * FF + fc];
    if (f < FF) A[(l * 650 + r) * FF + f] = acc;
  } else {
    const float* pb = postb + l * FF;
    for (int j = 0; j < FF; ++j) acc += pb[j] * lw[j * FF + fc];
    if (f < FF) bias2[l * 64 + f] = acc + linb[l * FF + f];
  }
}

// ---------------- pack A into bf16 [l][chunk 13][col 64][k 64] ----------------
__global__ void k_packA(const float* __restrict__ Af, short* __restrict__ Abt) {
  int t = blockIdx.x * 256 + threadIdx.x;
  if (t >= 3 * 13 * 64 * 64) return;
  int kk = t & 63;
  int f = (t >> 6) & 63;
  int lc = t >> 12;
  int c = lc % 13;
  int l = lc / 13;
  float v = 0.f;
  if (kk < FF && f < FF) v = Af[((size_t)(l * 650 + c * FF + kk)) * FF + f];
  Abt[t] = f2bf(v);
}

// ---------------- GCN: p = (x @ W_gcn) * dinv  (bf16, row stride 64) ----------------
__global__ void k_gcnpre(const float* __restrict__ x, const float* __restrict__ Wg,
                         const float* __restrict__ dinv, short* __restrict__ pb) {
  int t = blockIdx.x * 256 + threadIdx.x;
  int n = t >> 6, f = t & 63;
  if (n >= NN) return;
  float v = 0.f;
  if (f < FF) v = (x[2 * n] * Wg[f] + x[2 * n + 1] * Wg[FF + f]) * dinv[n];
  pb[n * 64 + f] = f2bf(v);
}

// ---------------- GCN aggregation (wave per node, 8-deep gather) ----------------
__global__ void k_gcnagg(const short* __restrict__ pb, const int* __restrict__ off,
                         const int* __restrict__ ssrc, const float* __restrict__ dinv,
                         const float* __restrict__ bg, float* __restrict__ h) {
  int wid = (blockIdx.x * blockDim.x + threadIdx.x) >> 6;
  int lane = threadIdx.x & 63;
  if (wid >= NN) return;
  int n = wid;
  int fc = lane < FF ? lane : FF - 1;
  float acc = bf2f(pb[n * 64 + fc]);  // self-loop term
  int lo = off[n], hi = off[n + 1];
  for (int base = lo; base < hi; base += 64) {
    int cnt = hi - base; if (cnt > 64) cnt = 64;
    int sidx = (base + lane < hi) ? ssrc[base + lane] : 0;
    for (int j = 0; j < cnt; j += 8) {
#pragma unroll
      for (int i = 0; i < 8; ++i) {
        int s = __shfl(sidx, j + i);
        float v = bf2f(pb[s * 64 + fc]);
        acc += (j + i < cnt) ? v : 0.f;
      }
    }
  }
  if (lane < FF) h[n * FF + lane] = dinv[n] * acc + bg[lane];
}

// ---------------- PNA pre: cb = h@WpT + bp (fp32), bb = h@WpB (bf16/64) ----------------
__global__ __launch_bounds__(256) void k_pre(const float* __restrict__ h, const float* __restrict__ preW,
                                             const float* __restrict__ preb, float* __restrict__ cb,
                                             short* __restrict__ bbh, int l) {
  int lane = threadIdx.x & 63;
  int fc = lane < FF ? lane : FF - 1;
  bool act = lane < FF;
  const float* WT = preW + l * 100 * FF;
  const float* WB = WT + FF * FF;
  float wT[FF], wB[FF];
#pragma unroll
  for (int k = 0; k < FF; ++k) { wT[k] = WT[k * FF + fc]; wB[k] = WB[k * FF + fc]; }
  float bp = preb[l * FF + fc];
  int nwaves = (gridDim.x * blockDim.x) >> 6;
  int wid = (blockIdx.x * blockDim.x + threadIdx.x) >> 6;
  for (int n = wid; n < NN; n += nwaves) {
    float hv = h[n * FF + fc];
    float ca = 0.f, ba = 0.f;
#pragma unroll
    for (int k = 0; k < FF; ++k) {
      float hk = __shfl(hv, k);
      ca += hk * wT[k];
      ba += hk * wB[k];
    }
    if (act) { cb[n * FF + lane] = ca + bp; bbh[n * 64 + lane] = f2bf(ba); }
  }
}

// ---------------- PNA aggregation (wave per node, 8-deep gather, bf16 out) ----------------
__global__ void k_agg(const short* __restrict__ bbh, const float* __restrict__ cb,
                      const int* __restrict__ off, const int* __restrict__ ssrc,
                      const float* __restrict__ lgc, const float* __restrict__ scal,
                      short* __restrict__ agb, float* __restrict__ ampatt) {
  int wid = (blockIdx.x * blockDim.x + threadIdx.x) >> 6;
  int lane = threadIdx.x & 63;
  if (wid >= NN) return;
  int n = wid;
  int fc = lane < FF ? lane : FF - 1;
  float S = 0.f, S2 = 0.f, MN = INFINITY, MX = -INFINITY;
  int lo = off[n], hi = off[n + 1];
  for (int base = lo; base < hi; base += 64) {
    int cnt = hi - base; if (cnt > 64) cnt = 64;
    int sidx = (base + lane < hi) ? ssrc[base + lane] : 0;
    for (int j = 0; j < cnt; j += 8) {
#pragma unroll
      for (int i = 0; i < 8; ++i) {
        int s = __shfl(sidx, j + i);
        float v = bf2f(bbh[s * 64 + fc]);
        bool ok = (j + i < cnt);
        if (ok) {
          S += v; S2 += v * v;
          MN = fminf(MN, v); MX = fmaxf(MX, v);
        }
      }
    }
  }
  int d = hi - lo;
  float mean, mnv, mxv, stdv;
  if (d > 0) {
    float inv = 1.f / (float)d;
    float m = S * inv;
    float var = S2 * inv - m * m; var = var > 0.f ? var : 0.f;
    stdv = sqrtf(var + 1e-5f);
    float c = cb[n * FF + fc];
    mean = c + m; mnv = c + MN; mxv = c + MX;
  } else {
    mean = 0.f; mnv = 0.f; mxv = 0.f; stdv = sqrtf(1e-5f);
  }
  short* row = agb + (size_t)n * 256;
  if (lane < FF) {
    row[lane] = f2bf(mean);
    row[64 + lane] = f2bf(mnv);
    row[128 + lane] = f2bf(mxv);
    row[192 + lane] = f2bf(stdv);
  } else {
    row[lane] = 0; row[64 + lane] = 0; row[128 + lane] = 0; row[192 + lane] = 0;
  }
  if (lane == 0) {
    float avg = scal[0] * (1.f / NN);
    float lg = lgc[n];
    ampatt[2 * n] = lg / avg;
    ampatt[2 * n + 1] = avg / lg;
  }
}

// ---------------- post GEMM (bf16 MFMA, factored amp/att) ----------------
// out = h@A0 + agg@A1 + amp*(agg@A2) + att*(agg@A3) + bias2
// Per block: 128 nodes x 64 cols; 5 K-chunks (h + 4 agg slices).
__global__ __launch_bounds__(256) void k_gemm(const float* __restrict__ h, const short* __restrict__ agb,
                                              const float* __restrict__ ampatt, const short* __restrict__ Abt,
                                              const float* __restrict__ bias2, float* __restrict__ out) {
  __shared__ short Xs[128][72];
  __shared__ short Bs[3][64][72];
  int tid = threadIdx.x;
  int n0 = blockIdx.x * 128;
  int w = tid >> 6, lane = tid & 63;
  int q = lane >> 4, m16 = lane & 15;

  // X staging role
  int nl = tid & 127;
  int kh = (tid >> 7) * 32;
  int n = n0 + nl;
  bool nvalid = n < NN;
  const float* hrow = h + (size_t)(nvalid ? n : 0) * FF;
  const short* arow = agb + (size_t)(nvalid ? n : 0) * 256;

  // B staging role
  int bf = tid >> 2;
  int bko = (tid & 3) * 16;

  f32x4 aB[2][4], aC[2][4], aD[2][4];
#pragma unroll
  for (int i = 0; i < 2; ++i)
#pragma unroll
    for (int j = 0; j < 4; ++j) {
      aB[i][j] = (f32x4){0.f, 0.f, 0.f, 0.f};
      aC[i][j] = (f32x4){0.f, 0.f, 0.f, 0.f};
      aD[i][j] = (f32x4){0.f, 0.f, 0.f, 0.f};
    }

  for (int c = 0; c < 5; ++c) {
    if (c) __syncthreads();
    // --- stage B: chunk 0 for c=0; chunks c, c+4, c+8 for c>=1 ---
    int nslice = (c == 0) ? 1 : 3;
    for (int s = 0; s < nslice; ++s) {
      int chunk = (c == 0) ? 0 : (c + 4 * s);
      const float4* g = (const float4*)(Abt + (chunk << 12) + (bf << 6) + bko);
      *(float4*)&Bs[s][bf][bko] = g[0];
      *(float4*)&Bs[s][bf][bko + 8] = g[1];
    }
    // --- stage X ---
    if (c == 0) {
#pragma unroll
      for (int j = 0; j < 32; j += 2) {
        int kk = kh + j;
        float2 v = {0.f, 0.f};
        if (nvalid && kk < FF) v = *(const float2*)(hrow + kk);
        Xs[nl][kk] = f2bf(v.x);
        Xs[nl][kk + 1] = f2bf(v.y);
      }
    } else {
      float4 v0 = {0,0,0,0}, v1 = {0,0,0,0}, v2 = {0,0,0,0}, v3 = {0,0,0,0};
      if (nvalid) {
        const float4* g = (const float4*)(arow + (c - 1) * 64 + kh);
        v0 = g[0]; v1 = g[1]; v2 = g[2]; v3 = g[3];
      }
      float4* dstp = (float4*)&Xs[nl][kh];
      dstp[0] = v0; dstp[1] = v1; dstp[2] = v2; dstp[3] = v3;
    }
    __syncthreads();
    // --- MFMA ---
#pragma unroll
    for (int hh = 0; hh < 2; ++hh) {
      int ko = hh * 32 + q * 8;
      bf16x8 a0 = *(const bf16x8*)&Xs[w * 32 + m16][ko];
      bf16x8 a1 = *(const bf16x8*)&Xs[w * 32 + 16 + m16][ko];
      if (c == 0) {
#pragma unroll
        for (int ft = 0; ft < 4; ++ft) {
          bf16x8 b = *(const bf16x8*)&Bs[0][ft * 16 + m16][ko];
          aB[0][ft] = __builtin_amdgcn_mfma_f32_16x16x32_bf16(a0, b, aB[0][ft], 0, 0, 0);
          aB[1][ft] = __builtin_amdgcn_mfma_f32_16x16x32_bf16(a1, b, aB[1][ft], 0, 0, 0);
        }
      } else {
#pragma unroll
        for (int ft = 0; ft < 4; ++ft) {
          bf16x8 b0 = *(const bf16x8*)&Bs[0][ft * 16 + m16][ko];
          bf16x8 b1 = *(const bf16x8*)&Bs[1][ft * 16 + m16][ko];
          bf16x8 b2 = *(const bf16x8*)&Bs[2][ft * 16 + m16][ko];
          aB[0][ft] = __builtin_amdgcn_mfma_f32_16x16x32_bf16(a0, b0, aB[0][ft], 0, 0, 0);
          aB[1][ft] = __builtin_amdgcn_mfma_f32_16x16x32_bf16(a1, b0, aB[1][ft], 0, 0, 0);
          aC[0][ft] = __builtin_amdgcn_mfma_f32_16x16x32_bf16(a0, b1, aC[0][ft], 0, 0, 0);
          aC[1][ft] = __builtin_amdgcn_mfma_f32_16x16x32_bf16(a1, b1, aC[1][ft], 0, 0, 0);
          aD[0][ft] = __builtin_amdgcn_mfma_f32_16x16x32_bf16(a0, b2, aD[0][ft], 0, 0, 0);
          aD[1][ft] = __builtin_amdgcn_mfma_f32_16x16x32_bf16(a1, b2, aD[1][ft], 0, 0, 0);
        }
      }
    }
  }
  // --- epilogue: out = aB + amp*aC + att*aD + bias2 ---
#pragma unroll
  for (int mt = 0; mt < 2; ++mt) {
#pragma unroll
    for (int r = 0; r < 4; ++r) {
      int node = n0 + w * 32 + mt * 16 + q * 4 + r;
      if (node >= NN) continue;
      float2 aa = *(const float2*)(ampatt + 2 * node);
#pragma unroll
      for (int ft = 0; ft < 4; ++ft) {
        int col = ft * 16 + m16;
        if (col >= FF) continue;
        out[node * FF + col] = aB[mt][ft][r] + aa.x * aC[mt][ft][r] + aa.y * aD[mt][ft][r] + bias2[col];
      }
    }
  }
}

// ---------------- BN stats ----------------
__global__ void k_bnred(const float* __restrict__ h, float* __restrict__ bnsum) {
  int lane = threadIdx.x & 63, w = threadIdx.x >> 6;
  int wid = (blockIdx.x * blockDim.x + threadIdx.x) >> 6;
  int nw = (gridDim.x * blockDim.x) >> 6;
  int fc = lane < FF ? lane : FF - 1;
  float s = 0.f, q = 0.f;
  for (int n = wid; n < NN; n += nw) {
    float v = h[n * FF + fc];
    s += v; q += v * v;
  }
  __shared__ float sm[2][4][64];
  sm[0][w][lane] = (lane < FF) ? s : 0.f;
  sm[1][w][lane] = (lane < FF) ? q : 0.f;
  __syncthreads();
  if (w == 0 && lane < FF) {
    float ts = sm[0][0][lane] + sm[0][1][lane] + sm[0][2][lane] + sm[0][3][lane];
    float tq = sm[1][0][lane] + sm[1][1][lane] + sm[1][2][lane] + sm[1][3][lane];
    atomicAdd(&bnsum[lane], ts);
    atomicAdd(&bnsum[64 + lane], tq);
  }
}

// ---------------- BN normalize + relu ----------------
__global__ void k_bnnorm(float* __restrict__ h, const float* __restrict__ bnsum,
                         const float* __restrict__ gamma, const float* __restrict__ beta, int l) {
  int t = blockIdx.x * 256 + threadIdx.x;
  int n = t >> 6, f = t & 63;
  if (n >= NN || f >= FF) return;
  float mu = bnsum[f] * (1.f / NN);
  float vq = bnsum[64 + f] * (1.f / NN) - mu * mu;
  float rs = rsqrtf((vq > 0.f ? vq : 0.f) + 1e-5f);
  float a = rs * gamma[l * FF + f];
  float b = beta[l * FF + f] - mu * a;
  float v = h[n * FF + f] * a + b;
  h[n * FF + f] = v > 0.f ? v : 0.f;
}

// ---------------- graph readout + MLP ----------------
__global__ void k_readout(const float* __restrict__ h, const int* __restrict__ batch,
                          const float* __restrict__ W1, const float* __restrict__ b1,
                          const float* __restrict__ W2, const float* __restrict__ b2,
                          float* __restrict__ out) {
  int g = blockIdx.x;
  __shared__ int bounds[2];
  __shared__ float gv[64];
  __shared__ float red[4][64];
  if (threadIdx.x == 0) {
    int lo = 0, hi = NN;
    while (lo < hi) { int m = (lo + hi) >> 1; if (batch[m] < g) lo = m + 1; else hi = m; }
    bounds[0] = lo;
    int lo2 = lo, hi2 = NN;
    while (lo2 < hi2) { int m = (lo2 + hi2) >> 1; if (batch[m] < g + 1) lo2 = m + 1; else hi2 = m; }
    bounds[1] = lo2;
  }
  __syncthreads();
  int lo = bounds[0], hi = bounds[1];
  int lane = threadIdx.x & 63, w = threadIdx.x >> 6;
  int fc = lane < FF ? lane : FF - 1;
  float acc = 0.f;
  for (int n = lo + w; n < hi; n += 4) acc += h[n * FF + fc];
  red[w][lane] = (lane < FF) ? acc : 0.f;
  __syncthreads();
  if (w == 0) gv[lane] = red[0][lane] + red[1][lane] + red[2][lane] + red[3][lane];
  __syncthreads();
  if (threadIdx.x < 64) {
    int j = threadIdx.x;
    float hj = 0.f;
    if (j < 25) {
      float a = b1[j];
      for (int f = 0; f < FF; ++f) a += gv[f] * W1[f * 25 + j];
      hj = (a > 0.f ? a : 0.f) * W2[j];
    }
    for (int o = 32; o > 0; o >>= 1) hj += __shfl_down(hj, o);
    if (j == 0) out[g] = hj + b2[0];
  }
}

extern "C" void kernel_launch(void* const* d_in, const int* in_sizes, int n_in,
                              void* d_out, int out_size, void* d_ws, size_t ws_size,
                              hipStream_t stream) {
  const float* x     = (const float*)d_in[0];
  const int*   ei    = (const int*)d_in[1];
  const int*   src   = ei;
  const int*   dst   = ei + NE;
  const int*   batch = (const int*)d_in[2];
  const float* Wg    = (const float*)d_in[3];
  const float* bg    = (const float*)d_in[4];
  const float* preW  = (const float*)d_in[5];
  const float* preb  = (const float*)d_in[6];
  const float* postW = (const float*)d_in[7];
  const float* postb = (const float*)d_in[8];
  const float* linW  = (const float*)d_in[9];
  const float* linb  = (const float*)d_in[10];
  const float* gamma = (const float*)d_in[11];
  const float* beta  = (const float*)d_in[12];
  const float* W1    = (const float*)d_in[13];
  const float* b1    = (const float*)d_in[14];
  const float* W2    = (const float*)d_in[15];
  const float* b2    = (const float*)d_in[16];
  float* out = (float*)d_out;

  char* W = (char*)d_ws;
  int*   deg    = (int*)(W + 0);           // 400384
  int*   cur    = (int*)(W + 400384);      // 400384
  int*   off    = (int*)(W + 800768);      // 400896
  int*   ssrc   = (int*)(W + 1201664);     // 6400000
  int*   parts  = (int*)(W + 7601664);     // 4096
  float* dinv   = (float*)(W + 7605760);   // 400384
  float* lgc    = (float*)(W + 8006144);   // 400384
  float* scal   = (float*)(W + 8406528);   // 512
  float* bnsum  = (float*)(W + 8407040);   // 2048
  float* Af     = (float*)(W + 8409088);   // 390144
  float* bias2  = (float*)(W + 8799232);   // 1024
  float* h0     = (float*)(W + 8800256);   // 20000256
  float* h1     = (float*)(W + 28800512);  // 20000256
  float* cb     = (float*)(W + 48800768);  // 20000256
  short* bbh    = (short*)(W + 68801024);  // 12800256 (bf16 [node][64]; also GCN p)
  short* agb    = (short*)(W + 81601280);  // 51200256 (bf16 [node][256])
  float* ampatt = (float*)(W + 132801536); // 800256
  short* Abt    = (short*)(W + 133601792); // 319488  (total ~133.9 MB)

  hipMemsetAsync(deg, 0, 800768, stream);   // deg + cur
  hipMemsetAsync(scal, 0, 2560, stream);    // scal + bnsum

  k_deg<<<(NE + 255) / 256, 256, 0, stream>>>(dst, deg);
  k_scan1<<<98, 1024, 0, stream>>>(deg, off, parts);
  k_scan2<<<1, 128, 0, stream>>>(parts, 98);
  k_scan3<<<(NN + 255) / 256, 256, 0, stream>>>(off, parts);
  k_nodeinit<<<(NN + 255) / 256, 256, 0, stream>>>(deg, dinv, lgc, scal);
  k_scatter<<<(NE + 255) / 256, 256, 0, stream>>>(src, dst, off, cur, ssrc);
  k_fusew<<<(3 * 651 + 3) / 4, 256, 0, stream>>>(postW, postb, linW, linb, Af, bias2);
  k_packA<<<(3 * 13 * 64 * 64 + 255) / 256, 256, 0, stream>>>(Af, Abt);

  k_gcnpre<<<NN / 4, 256, 0, stream>>>(x, Wg, dinv, bbh);
  k_gcnagg<<<NN / 4, 256, 0, stream>>>(bbh, off, ssrc, dinv, bg, h0);

  float* hin = h0;
  float* hout = h1;
  for (int l = 0; l < NL; ++l) {
    k_pre<<<1024, 256, 0, stream>>>(hin, preW, preb, cb, bbh, l);
    k_agg<<<NN / 4, 256, 0, stream>>>(bbh, cb, off, ssrc, lgc, scal, agb, ampatt);
    k_gemm<<<(NN + 127) / 128, 256, 0, stream>>>(hin, agb, ampatt, Abt + l * 13 * 64 * 64, bias2 + l * 64, hout);
    k_bnred<<<256, 256, 0, stream>>>(hout, bnsum + l * 128);
    k_bnnorm<<<NN / 4, 256, 0, stream>>>(hout, bnsum + l * 128, gamma, beta, l);
    float* t = hin; hin = hout; hout = t;
  }
  k_readout<<<NG, 256, 0, stream>>>(hin, batch, W1, b1, W2, b2, out);
}

// Round 4
// 942.924 us; speedup vs baseline: 2.1345x; 1.3398x over previous
//
#include <hip/hip_runtime.h>
#include <math.h>

#define NN 100000
#define NE 1600000
#define NG 64
#define FF 50
#define NL 3
#define NBUCK ((NN + 255) / 256)   // 391

typedef short bf16x8 __attribute__((ext_vector_type(8)));
typedef float f32x4 __attribute__((ext_vector_type(4)));

__device__ __forceinline__ short f2bf(float f) {
  return __builtin_bit_cast(short, (__bf16)f);
}
__device__ __forceinline__ float bf2f(short s) {
  unsigned int u = ((unsigned int)(unsigned short)s) << 16;
  return __builtin_bit_cast(float, u);
}

// ---------------- degree ----------------
__global__ void k_deg(const int* __restrict__ dst, int* __restrict__ deg) {
  int e = blockIdx.x * blockDim.x + threadIdx.x;
  if (e < NE) atomicAdd(&deg[dst[e]], 1);
}

// ---------------- prefix scan ----------------
__global__ void k_scan1(const int* __restrict__ deg, int* __restrict__ off, int* __restrict__ parts) {
  __shared__ int sm[1024];
  int i = blockIdx.x * 1024 + threadIdx.x;
  int v = (i < NN) ? deg[i] : 0;
  sm[threadIdx.x] = v;
  __syncthreads();
  for (int ofs = 1; ofs < 1024; ofs <<= 1) {
    int t = (threadIdx.x >= ofs) ? sm[threadIdx.x - ofs] : 0;
    __syncthreads();
    sm[threadIdx.x] += t;
    __syncthreads();
  }
  if (i < NN) off[i] = sm[threadIdx.x] - v;
  if (threadIdx.x == 1023) parts[blockIdx.x] = sm[1023];
}

__global__ void k_scan2(int* __restrict__ parts, int nb) {
  __shared__ int sm[128];
  int v = (threadIdx.x < nb) ? parts[threadIdx.x] : 0;
  sm[threadIdx.x] = v;
  __syncthreads();
  for (int ofs = 1; ofs < 128; ofs <<= 1) {
    int t = (threadIdx.x >= ofs) ? sm[threadIdx.x - ofs] : 0;
    __syncthreads();
    sm[threadIdx.x] += t;
    __syncthreads();
  }
  if (threadIdx.x < nb) parts[threadIdx.x] = sm[threadIdx.x] - v;
}

__global__ void k_scan3(int* __restrict__ off, const int* __restrict__ parts, int* __restrict__ bcur) {
  int i = blockIdx.x * 256 + threadIdx.x;
  if (i < NN) {
    int v = off[i] + parts[i >> 10];
    off[i] = v;
    if ((i & 255) == 0) bcur[i >> 8] = v;   // bucket write cursor = CSR base of bucket
  }
  if (i == 0) off[NN] = NE;
}

// ---------------- node init ----------------
__global__ void k_nodeinit(const int* __restrict__ deg, float* __restrict__ dinv,
                           float* __restrict__ lgc, float* __restrict__ scal) {
  int i = blockIdx.x * 256 + threadIdx.x;
  float lp = 0.f;
  if (i < NN) {
    int d = deg[i];
    dinv[i] = rsqrtf((float)(d + 1));
    int dc = d > 1 ? d : 1;
    lgc[i] = log1pf((float)dc);
    lp = log1pf((float)d);
  }
  for (int o = 32; o > 0; o >>= 1) lp += __shfl_down(lp, o);
  __shared__ float red[4];
  int lane = threadIdx.x & 63, w = threadIdx.x >> 6;
  if (lane == 0) red[w] = lp;
  __syncthreads();
  if (threadIdx.x == 0) atomicAdd(scal, red[0] + red[1] + red[2] + red[3]);
}

// ---------------- phase A: bin edges into 391 CSR-aligned buckets ----------------
// tmp entry: (dst&255)<<17 | src   (src<2^17, dloc<2^8 => 25 bits)
__global__ __launch_bounds__(256) void k_bucket(const int* __restrict__ src, const int* __restrict__ dst,
                                                int* __restrict__ bcur, unsigned* __restrict__ tmp) {
  __shared__ int hist[NBUCK];
  __shared__ int base[NBUCK];
  int t = threadIdx.x;
  for (int i = t; i < NBUCK; i += 256) hist[i] = 0;
  __syncthreads();
  int e0 = blockIdx.x * 4096;
  int myb[16], myrank[16];
  unsigned mypack[16];
#pragma unroll
  for (int i = 0; i < 16; ++i) {
    int e = e0 + i * 256 + t;
    if (e < NE) {
      int s = src[e], d = dst[e];
      int b = d >> 8;
      myb[i] = b;
      mypack[i] = ((unsigned)(d & 255) << 17) | (unsigned)s;
      myrank[i] = atomicAdd(&hist[b], 1);
    } else myb[i] = -1;
  }
  __syncthreads();
  for (int i = t; i < NBUCK; i += 256)
    base[i] = hist[i] ? atomicAdd(&bcur[i], hist[i]) : 0;
  __syncthreads();
#pragma unroll
  for (int i = 0; i < 16; ++i)
    if (myb[i] >= 0) tmp[base[myb[i]] + myrank[i]] = mypack[i];
}

// ---------------- phase B: sort each bucket into final CSR ----------------
__global__ __launch_bounds__(256) void k_bsort(const int* __restrict__ off, const unsigned* __restrict__ tmp,
                                               int* __restrict__ ssrc) {
  int b = blockIdx.x;
  int n0 = b * 256;
  int nEnd = n0 + 256 < NN ? n0 + 256 : NN;
  __shared__ int cnt[256];
  __shared__ int nb[256];
  int t = threadIdx.x;
  cnt[t] = 0;
  if (n0 + t < nEnd) nb[t] = off[n0 + t];
  __syncthreads();
  int lo = off[n0], hiE = off[nEnd];
  for (int e = lo + t; e < hiE; e += 256) {
    unsigned p = tmp[e];
    int dloc = p >> 17;
    int s = (int)(p & 0x1FFFFu);
    int pos = nb[dloc] + atomicAdd(&cnt[dloc], 1);
    ssrc[pos] = s;
  }
}

// ---------------- fuse post_W @ lin_W ----------------
__global__ void k_fusew(const float* __restrict__ postW, const float* __restrict__ postb,
                        const float* __restrict__ linW, const float* __restrict__ linb,
                        float* __restrict__ A, float* __restrict__ bias2) {
  int wid = (blockIdx.x * blockDim.x + threadIdx.x) >> 6;
  int f = threadIdx.x & 63;
  if (wid >= 3 * 651) return;
  int l = wid / 651, r = wid % 651;
  int fc = f < FF ? f : FF - 1;
  const float* lw = linW + l * FF * FF;
  float acc = 0.f;
  if (r < 650) {
    const float* pw = postW + (l * 650 + r) * FF;
    for (int j = 0; j < FF; ++j) acc += pw[j] * lw[j * FF + fc];
    if (f < FF) A[(l * 650 + r) * FF + f] = acc;
  } else {
    const float* pb = postb + l * FF;
    for (int j = 0; j < FF; ++j) acc += pb[j] * lw[j * FF + fc];
    if (f < FF) bias2[l * 64 + f] = acc + linb[l * FF + f];
  }
}

// ---------------- pack fused A into bf16 [l][chunk 13][col 64][k 64] ----------------
__global__ void k_packA(const float* __restrict__ Af, short* __restrict__ Abt) {
  int t = blockIdx.x * 256 + threadIdx.x;
  if (t >= 3 * 13 * 64 * 64) return;
  int kk = t & 63;
  int f = (t >> 6) & 63;
  int lc = t >> 12;
  int c = lc % 13;
  int l = lc / 13;
  float v = 0.f;
  if (kk < FF && f < FF) v = Af[((size_t)(l * 650 + c * FF + kk)) * FF + f];
  Abt[t] = f2bf(v);
}

// ---------------- pack pre_W into bf16 [l][half 2][col 64][k 64] ----------------
__global__ void k_packP(const float* __restrict__ preW, short* __restrict__ Pbt) {
  int t = blockIdx.x * 256 + threadIdx.x;
  if (t >= NL * 2 * 64 * 64) return;
  int kk = t & 63;
  int f = (t >> 6) & 63;
  int ls = t >> 12;
  int s = ls & 1, l = ls >> 1;
  float v = 0.f;
  if (kk < FF && f < FF) v = preW[(size_t)(l * 100 + s * FF + kk) * FF + f];
  Pbt[t] = f2bf(v);
}

// ---------------- GCN: p = (x @ W_gcn) * dinv  (bf16, row stride 64) ----------------
__global__ void k_gcnpre(const float* __restrict__ x, const float* __restrict__ Wg,
                         const float* __restrict__ dinv, short* __restrict__ pb) {
  int t = blockIdx.x * 256 + threadIdx.x;
  int n = t >> 6, f = t & 63;
  if (n >= NN) return;
  float v = 0.f;
  if (f < FF) v = (x[2 * n] * Wg[f] + x[2 * n + 1] * Wg[FF + f]) * dinv[n];
  pb[n * 64 + f] = f2bf(v);
}

// ---------------- GCN aggregation (wave per node, readlane broadcast) ----------------
__global__ void k_gcnagg(const short* __restrict__ pb, const int* __restrict__ off,
                         const int* __restrict__ ssrc, const float* __restrict__ dinv,
                         const float* __restrict__ bg, float* __restrict__ h) {
  int wid = (blockIdx.x * blockDim.x + threadIdx.x) >> 6;
  int lane = threadIdx.x & 63;
  if (wid >= NN) return;
  int n = wid;
  int fc = lane < FF ? lane : FF - 1;
  float acc = bf2f(pb[n * 64 + fc]);  // self-loop term
  int lo = off[n], hi = off[n + 1];
  for (int base = lo; base < hi; base += 64) {
    int rem = hi - base;
    int cnt = rem > 64 ? 64 : rem;
    int sidx = (base + lane < hi) ? ssrc[base + lane] : 0;
    int full = cnt & ~7;
    int j = 0;
    for (; j < full; j += 8) {
#pragma unroll
      for (int i = 0; i < 8; ++i) {
        int s = __builtin_amdgcn_readlane(sidx, j + i);
        acc += bf2f(pb[s * 64 + fc]);
      }
    }
    for (; j < cnt; ++j) {
      int s = __builtin_amdgcn_readlane(sidx, j);
      acc += bf2f(pb[s * 64 + fc]);
    }
  }
  if (lane < FF) h[n * FF + lane] = dinv[n] * acc + bg[lane];
}

// ---------------- PNA pre (MFMA): cb = h@WpT + bp (fp32), bbh = h@WpB (bf16/64) ----------------
// Optional fused BN+ReLU on input: v = relu(a*v + b) with ab[64] per-feature.
__global__ __launch_bounds__(256) void k_preM(const float* __restrict__ hin, const float2* __restrict__ ab,
                                              const short* __restrict__ Pbt, const float* __restrict__ preb,
                                              float* __restrict__ cb, short* __restrict__ bbh, int l) {
  __shared__ short Xs[128][72];
  __shared__ short Bs[2][64][72];
  int tid = threadIdx.x;
  int n0 = blockIdx.x * 128;
  int w = tid >> 6, lane = tid & 63;
  int q = lane >> 4, m16 = lane & 15;

  // stage B (both halves)
  int bf = tid >> 2, bko = (tid & 3) * 16;
  const short* Pl = Pbt + l * 2 * 4096;
  for (int s = 0; s < 2; ++s) {
    const float4* g = (const float4*)(Pl + (s << 12) + (bf << 6) + bko);
    *(float4*)&Bs[s][bf][bko] = g[0];
    *(float4*)&Bs[s][bf][bko + 8] = g[1];
  }
  // stage X
  int nl = tid & 127, kh = (tid >> 7) * 32;
  int n = n0 + nl;
  bool nvalid = n < NN;
  const float* hrow = hin + (size_t)(nvalid ? n : 0) * FF;
#pragma unroll
  for (int j = 0; j < 32; j += 2) {
    int kk = kh + j;
    float2 v = {0.f, 0.f};
    if (nvalid && kk < FF) v = *(const float2*)(hrow + kk);
    if (ab) {
      float2 p0 = ab[kk], p1 = ab[kk + 1];
      v.x = fmaxf(fmaf(v.x, p0.x, p0.y), 0.f);
      v.y = fmaxf(fmaf(v.y, p1.x, p1.y), 0.f);
    }
    Xs[nl][kk] = f2bf(v.x);
    Xs[nl][kk + 1] = f2bf(v.y);
  }
  __syncthreads();

  f32x4 aT[2][4], aB2[2][4];
#pragma unroll
  for (int i = 0; i < 2; ++i)
#pragma unroll
    for (int j = 0; j < 4; ++j) {
      aT[i][j] = (f32x4){0.f, 0.f, 0.f, 0.f};
      aB2[i][j] = (f32x4){0.f, 0.f, 0.f, 0.f};
    }
#pragma unroll
  for (int hh = 0; hh < 2; ++hh) {
    int ko = hh * 32 + q * 8;
    bf16x8 a0 = *(const bf16x8*)&Xs[w * 32 + m16][ko];
    bf16x8 a1 = *(const bf16x8*)&Xs[w * 32 + 16 + m16][ko];
#pragma unroll
    for (int ft = 0; ft < 4; ++ft) {
      bf16x8 b0 = *(const bf16x8*)&Bs[0][ft * 16 + m16][ko];
      bf16x8 b1 = *(const bf16x8*)&Bs[1][ft * 16 + m16][ko];
      aT[0][ft] = __builtin_amdgcn_mfma_f32_16x16x32_bf16(a0, b0, aT[0][ft], 0, 0, 0);
      aT[1][ft] = __builtin_amdgcn_mfma_f32_16x16x32_bf16(a1, b0, aT[1][ft], 0, 0, 0);
      aB2[0][ft] = __builtin_amdgcn_mfma_f32_16x16x32_bf16(a0, b1, aB2[0][ft], 0, 0, 0);
      aB2[1][ft] = __builtin_amdgcn_mfma_f32_16x16x32_bf16(a1, b1, aB2[1][ft], 0, 0, 0);
    }
  }
  // epilogue
#pragma unroll
  for (int mt = 0; mt < 2; ++mt) {
#pragma unroll
    for (int r = 0; r < 4; ++r) {
      int node = n0 + w * 32 + mt * 16 + q * 4 + r;
      if (node >= NN) continue;
#pragma unroll
      for (int ft = 0; ft < 4; ++ft) {
        int col = ft * 16 + m16;
        if (col < FF) cb[node * FF + col] = aT[mt][ft][r] + preb[l * FF + col];
        bbh[node * 64 + col] = f2bf(aB2[mt][ft][r]);  // cols>=50 are 0 (zero-padded B)
      }
    }
  }
}

// ---------------- PNA aggregation (wave per node, readlane, bf16 out) ----------------
__global__ void k_agg(const short* __restrict__ bbh, const float* __restrict__ cb,
                      const int* __restrict__ off, const int* __restrict__ ssrc,
                      const float* __restrict__ lgc, const float* __restrict__ scal,
                      short* __restrict__ agb, float* __restrict__ ampatt) {
  int wid = (blockIdx.x * blockDim.x + threadIdx.x) >> 6;
  int lane = threadIdx.x & 63;
  if (wid >= NN) return;
  int n = wid;
  int fc = lane < FF ? lane : FF - 1;
  float S = 0.f, S2 = 0.f, MN = INFINITY, MX = -INFINITY;
  int lo = off[n], hi = off[n + 1];
  for (int base = lo; base < hi; base += 64) {
    int rem = hi - base;
    int cnt = rem > 64 ? 64 : rem;
    int sidx = (base + lane < hi) ? ssrc[base + lane] : 0;
    int full = cnt & ~7;
    int j = 0;
    for (; j < full; j += 8) {
#pragma unroll
      for (int i = 0; i < 8; ++i) {
        int s = __builtin_amdgcn_readlane(sidx, j + i);
        float v = bf2f(bbh[s * 64 + fc]);
        S += v; S2 = fmaf(v, v, S2);
        MN = fminf(MN, v); MX = fmaxf(MX, v);
      }
    }
    for (; j < cnt; ++j) {
      int s = __builtin_amdgcn_readlane(sidx, j);
      float v = bf2f(bbh[s * 64 + fc]);
      S += v; S2 = fmaf(v, v, S2);
      MN = fminf(MN, v); MX = fmaxf(MX, v);
    }
  }
  int d = hi - lo;
  float mean, mnv, mxv, stdv;
  if (d > 0) {
    float inv = 1.f / (float)d;
    float m = S * inv;
    float var = S2 * inv - m * m; var = var > 0.f ? var : 0.f;
    stdv = sqrtf(var + 1e-5f);
    float c = cb[n * FF + fc];
    mean = c + m; mnv = c + MN; mxv = c + MX;
  } else {
    mean = 0.f; mnv = 0.f; mxv = 0.f; stdv = sqrtf(1e-5f);
  }
  short* row = agb + (size_t)n * 256;
  if (lane < FF) {
    row[lane] = f2bf(mean);
    row[64 + lane] = f2bf(mnv);
    row[128 + lane] = f2bf(mxv);
    row[192 + lane] = f2bf(stdv);
  } else {
    row[lane] = 0; row[64 + lane] = 0; row[128 + lane] = 0; row[192 + lane] = 0;
  }
  if (lane == 0) {
    float avg = scal[0] * (1.f / NN);
    float lg = lgc[n];
    ampatt[2 * n] = lg / avg;
    ampatt[2 * n + 1] = avg / lg;
  }
}

// ---------------- post GEMM (bf16 MFMA, factored amp/att, optional fused BN on h) ----------------
__global__ __launch_bounds__(256) void k_gemm(const float* __restrict__ h, const float2* __restrict__ ab,
                                              const short* __restrict__ agb, const float* __restrict__ ampatt,
                                              const short* __restrict__ Abt, const float* __restrict__ bias2,
                                              float* __restrict__ out) {
  __shared__ short Xs[128][72];
  __shared__ short Bs[3][64][72];
  int tid = threadIdx.x;
  int n0 = blockIdx.x * 128;
  int w = tid >> 6, lane = tid & 63;
  int q = lane >> 4, m16 = lane & 15;

  int nl = tid & 127;
  int kh = (tid >> 7) * 32;
  int n = n0 + nl;
  bool nvalid = n < NN;
  const float* hrow = h + (size_t)(nvalid ? n : 0) * FF;
  const short* arow = agb + (size_t)(nvalid ? n : 0) * 256;

  int bf = tid >> 2;
  int bko = (tid & 3) * 16;

  f32x4 aB[2][4], aC[2][4], aD[2][4];
#pragma unroll
  for (int i = 0; i < 2; ++i)
#pragma unroll
    for (int j = 0; j < 4; ++j) {
      aB[i][j] = (f32x4){0.f, 0.f, 0.f, 0.f};
      aC[i][j] = (f32x4){0.f, 0.f, 0.f, 0.f};
      aD[i][j] = (f32x4){0.f, 0.f, 0.f, 0.f};
    }

  for (int c = 0; c < 5; ++c) {
    if (c) __syncthreads();
    int nslice = (c == 0) ? 1 : 3;
    for (int s = 0; s < nslice; ++s) {
      int chunk = (c == 0) ? 0 : (c + 4 * s);
      const float4* g = (const float4*)(Abt + (chunk << 12) + (bf << 6) + bko);
      *(float4*)&Bs[s][bf][bko] = g[0];
      *(float4*)&Bs[s][bf][bko + 8] = g[1];
    }
    if (c == 0) {
#pragma unroll
      for (int j = 0; j < 32; j += 2) {
        int kk = kh + j;
        float2 v = {0.f, 0.f};
        if (nvalid && kk < FF) v = *(const float2*)(hrow + kk);
        if (ab) {
          float2 p0 = ab[kk], p1 = ab[kk + 1];
          v.x = fmaxf(fmaf(v.x, p0.x, p0.y), 0.f);
          v.y = fmaxf(fmaf(v.y, p1.x, p1.y), 0.f);
        }
        Xs[nl][kk] = f2bf(v.x);
        Xs[nl][kk + 1] = f2bf(v.y);
      }
    } else {
      float4 v0 = {0,0,0,0}, v1 = {0,0,0,0}, v2 = {0,0,0,0}, v3 = {0,0,0,0};
      if (nvalid) {
        const float4* g = (const float4*)(arow + (c - 1) * 64 + kh);
        v0 = g[0]; v1 = g[1]; v2 = g[2]; v3 = g[3];
      }
      float4* dstp = (float4*)&Xs[nl][kh];
      dstp[0] = v0; dstp[1] = v1; dstp[2] = v2; dstp[3] = v3;
    }
    __syncthreads();
#pragma unroll
    for (int hh = 0; hh < 2; ++hh) {
      int ko = hh * 32 + q * 8;
      bf16x8 a0 = *(const bf16x8*)&Xs[w * 32 + m16][ko];
      bf16x8 a1 = *(const bf16x8*)&Xs[w * 32 + 16 + m16][ko];
      if (c == 0) {
#pragma unroll
        for (int ft = 0; ft < 4; ++ft) {
          bf16x8 b = *(const bf16x8*)&Bs[0][ft * 16 + m16][ko];
          aB[0][ft] = __builtin_amdgcn_mfma_f32_16x16x32_bf16(a0, b, aB[0][ft], 0, 0, 0);
          aB[1][ft] = __builtin_amdgcn_mfma_f32_16x16x32_bf16(a1, b, aB[1][ft], 0, 0, 0);
        }
      } else {
#pragma unroll
        for (int ft = 0; ft < 4; ++ft) {
          bf16x8 b0 = *(const bf16x8*)&Bs[0][ft * 16 + m16][ko];
          bf16x8 b1 = *(const bf16x8*)&Bs[1][ft * 16 + m16][ko];
          bf16x8 b2 = *(const bf16x8*)&Bs[2][ft * 16 + m16][ko];
          aB[0][ft] = __builtin_amdgcn_mfma_f32_16x16x32_bf16(a0, b0, aB[0][ft], 0, 0, 0);
          aB[1][ft] = __builtin_amdgcn_mfma_f32_16x16x32_bf16(a1, b0, aB[1][ft], 0, 0, 0);
          aC[0][ft] = __builtin_amdgcn_mfma_f32_16x16x32_bf16(a0, b1, aC[0][ft], 0, 0, 0);
          aC[1][ft] = __builtin_amdgcn_mfma_f32_16x16x32_bf16(a1, b1, aC[1][ft], 0, 0, 0);
          aD[0][ft] = __builtin_amdgcn_mfma_f32_16x16x32_bf16(a0, b2, aD[0][ft], 0, 0, 0);
          aD[1][ft] = __builtin_amdgcn_mfma_f32_16x16x32_bf16(a1, b2, aD[1][ft], 0, 0, 0);
        }
      }
    }
  }
#pragma unroll
  for (int mt = 0; mt < 2; ++mt) {
#pragma unroll
    for (int r = 0; r < 4; ++r) {
      int node = n0 + w * 32 + mt * 16 + q * 4 + r;
      if (node >= NN) continue;
      float2 aa = *(const float2*)(ampatt + 2 * node);
#pragma unroll
      for (int ft = 0; ft < 4; ++ft) {
        int col = ft * 16 + m16;
        if (col >= FF) continue;
        out[node * FF + col] = aB[mt][ft][r] + aa.x * aC[mt][ft][r] + aa.y * aD[mt][ft][r] + bias2[col];
      }
    }
  }
}

// ---------------- BN stats ----------------
__global__ void k_bnred(const float* __restrict__ h, float* __restrict__ bnsum) {
  int lane = threadIdx.x & 63, w = threadIdx.x >> 6;
  int wid = (blockIdx.x * blockDim.x + threadIdx.x) >> 6;
  int nw = (gridDim.x * blockDim.x) >> 6;
  int fc = lane < FF ? lane : FF - 1;
  float s = 0.f, q = 0.f;
  for (int n = wid; n < NN; n += nw) {
    float v = h[n * FF + fc];
    s += v; q += v * v;
  }
  __shared__ float sm[2][4][64];
  sm[0][w][lane] = (lane < FF) ? s : 0.f;
  sm[1][w][lane] = (lane < FF) ? q : 0.f;
  __syncthreads();
  if (w == 0 && lane < FF) {
    float ts = sm[0][0][lane] + sm[0][1][lane] + sm[0][2][lane] + sm[0][3][lane];
    float tq = sm[1][0][lane] + sm[1][1][lane] + sm[1][2][lane] + sm[1][3][lane];
    atomicAdd(&bnsum[lane], ts);
    atomicAdd(&bnsum[64 + lane], tq);
  }
}

// ---------------- BN coeffs: a = rs*gamma, b = beta - mu*a ----------------
__global__ void k_bnab(const float* __restrict__ bnsum, const float* __restrict__ gamma,
                       const float* __restrict__ beta, float2* __restrict__ ab, int l) {
  int f = threadIdx.x;
  float a = 0.f, b = 0.f;
  if (f < FF) {
    float mu = bnsum[f] * (1.f / NN);
    float vq = bnsum[64 + f] * (1.f / NN) - mu * mu;
    float rs = rsqrtf((vq > 0.f ? vq : 0.f) + 1e-5f);
    a = rs * gamma[l * FF + f];
    b = beta[l * FF + f] - mu * a;
  }
  ab[f] = make_float2(a, b);
}

// ---------------- BN normalize + relu (layer 2 only, in place) ----------------
__global__ void k_bnnorm(float* __restrict__ h, const float* __restrict__ bnsum,
                         const float* __restrict__ gamma, const float* __restrict__ beta, int l) {
  int t = blockIdx.x * 256 + threadIdx.x;
  int n = t >> 6, f = t & 63;
  if (n >= NN || f >= FF) return;
  float mu = bnsum[f] * (1.f / NN);
  float vq = bnsum[64 + f] * (1.f / NN) - mu * mu;
  float rs = rsqrtf((vq > 0.f ? vq : 0.f) + 1e-5f);
  float a = rs * gamma[l * FF + f];
  float b = beta[l * FF + f] - mu * a;
  float v = h[n * FF + f] * a + b;
  h[n * FF + f] = v > 0.f ? v : 0.f;
}

// ---------------- graph readout + MLP ----------------
__global__ void k_readout(const float* __restrict__ h, const int* __restrict__ batch,
                          const float* __restrict__ W1, const float* __restrict__ b1,
                          const float* __restrict__ W2, const float* __restrict__ b2,
                          float* __restrict__ out) {
  int g = blockIdx.x;
  __shared__ int bounds[2];
  __shared__ float gv[64];
  __shared__ float red[4][64];
  if (threadIdx.x == 0) {
    int lo = 0, hi = NN;
    while (lo < hi) { int m = (lo + hi) >> 1; if (batch[m] < g) lo = m + 1; else hi = m; }
    bounds[0] = lo;
    int lo2 = lo, hi2 = NN;
    while (lo2 < hi2) { int m = (lo2 + hi2) >> 1; if (batch[m] < g + 1) lo2 = m + 1; else hi2 = m; }
    bounds[1] = lo2;
  }
  __syncthreads();
  int lo = bounds[0], hi = bounds[1];
  int lane = threadIdx.x & 63, w = threadIdx.x >> 6;
  int fc = lane < FF ? lane : FF - 1;
  float acc = 0.f;
  for (int n = lo + w; n < hi; n += 4) acc += h[n * FF + fc];
  red[w][lane] = (lane < FF) ? acc : 0.f;
  __syncthreads();
  if (w == 0) gv[lane] = red[0][lane] + red[1][lane] + red[2][lane] + red[3][lane];
  __syncthreads();
  if (threadIdx.x < 64) {
    int j = threadIdx.x;
    float hj = 0.f;
    if (j < 25) {
      float a = b1[j];
      for (int f = 0; f < FF; ++f) a += gv[f] * W1[f * 25 + j];
      hj = (a > 0.f ? a : 0.f) * W2[j];
    }
    for (int o = 32; o > 0; o >>= 1) hj += __shfl_down(hj, o);
    if (j == 0) out[g] = hj + b2[0];
  }
}

extern "C" void kernel_launch(void* const* d_in, const int* in_sizes, int n_in,
                              void* d_out, int out_size, void* d_ws, size_t ws_size,
                              hipStream_t stream) {
  const float* x     = (const float*)d_in[0];
  const int*   ei    = (const int*)d_in[1];
  const int*   src   = ei;
  const int*   dst   = ei + NE;
  const int*   batch = (const int*)d_in[2];
  const float* Wg    = (const float*)d_in[3];
  const float* bg    = (const float*)d_in[4];
  const float* preW  = (const float*)d_in[5];
  const float* preb  = (const float*)d_in[6];
  const float* postW = (const float*)d_in[7];
  const float* postb = (const float*)d_in[8];
  const float* linW  = (const float*)d_in[9];
  const float* linb  = (const float*)d_in[10];
  const float* gamma = (const float*)d_in[11];
  const float* beta  = (const float*)d_in[12];
  const float* W1    = (const float*)d_in[13];
  const float* b1    = (const float*)d_in[14];
  const float* W2    = (const float*)d_in[15];
  const float* b2    = (const float*)d_in[16];
  float* out = (float*)d_out;

  char* W = (char*)d_ws;
  int*    deg    = (int*)(W + 0);           // 400384
  int*    off    = (int*)(W + 400384);      // 400896
  int*    bcur   = (int*)(W + 801280);      // 2048
  int*    parts  = (int*)(W + 803328);      // 4096
  float*  dinv   = (float*)(W + 807424);    // 400384
  float*  lgc    = (float*)(W + 1207808);   // 400384
  float*  scal   = (float*)(W + 1608192);   // 512
  float*  bnsum  = (float*)(W + 1608704);   // 2048
  float2* ab     = (float2*)(W + 1610752);  // 1024 (2 layers x 64 float2)
  float*  Af     = (float*)(W + 1611776);   // 390144
  float*  bias2  = (float*)(W + 2001920);   // 1024
  short*  Abt    = (short*)(W + 2002944);   // 319488
  short*  Pbt    = (short*)(W + 2322432);   // 49152
  unsigned* tmp  = (unsigned*)(W + 2371584);// 6400000
  int*    ssrc   = (int*)(W + 8771584);     // 6400000
  float*  hA     = (float*)(W + 15171584);  // 20000256
  float*  hB     = (float*)(W + 35171840);  // 20000256
  float*  cb     = (float*)(W + 55172096);  // 20000256
  short*  bbh    = (short*)(W + 75172352);  // 12800256
  short*  agb    = (short*)(W + 87972608);  // 51200256
  float*  ampatt = (float*)(W + 139172864); // 800256  (total ~140 MB)

  hipMemsetAsync(deg, 0, 400384, stream);
  hipMemsetAsync(scal, 0, 2560, stream);    // scal + bnsum

  k_deg<<<(NE + 255) / 256, 256, 0, stream>>>(dst, deg);
  k_scan1<<<98, 1024, 0, stream>>>(deg, off, parts);
  k_scan2<<<1, 128, 0, stream>>>(parts, 98);
  k_scan3<<<(NN + 255) / 256, 256, 0, stream>>>(off, parts, bcur);
  k_nodeinit<<<(NN + 255) / 256, 256, 0, stream>>>(deg, dinv, lgc, scal);
  k_bucket<<<(NE + 4095) / 4096, 256, 0, stream>>>(src, dst, bcur, tmp);
  k_bsort<<<NBUCK, 256, 0, stream>>>(off, tmp, ssrc);
  k_fusew<<<(3 * 651 + 3) / 4, 256, 0, stream>>>(postW, postb, linW, linb, Af, bias2);
  k_packA<<<(3 * 13 * 64 * 64 + 255) / 256, 256, 0, stream>>>(Af, Abt);
  k_packP<<<(NL * 2 * 64 * 64 + 255) / 256, 256, 0, stream>>>(preW, Pbt);

  k_gcnpre<<<NN / 4, 256, 0, stream>>>(x, Wg, dinv, bbh);
  k_gcnagg<<<NN / 4, 256, 0, stream>>>(bbh, off, ssrc, dinv, bg, hA);

  float* hin = hA;
  float* hout = hB;
  for (int l = 0; l < NL; ++l) {
    const float2* abl = (l == 0) ? nullptr : (ab + (l - 1) * 64);
    k_preM<<<(NN + 127) / 128, 256, 0, stream>>>(hin, abl, Pbt, preb, cb, bbh, l);
    k_agg<<<NN / 4, 256, 0, stream>>>(bbh, cb, off, ssrc, lgc, scal, agb, ampatt);
    k_gemm<<<(NN + 127) / 128, 256, 0, stream>>>(hin, abl, agb, ampatt, Abt + l * 13 * 4096, bias2 + l * 64, hout);
    k_bnred<<<256, 256, 0, stream>>>(hout, bnsum + l * 128);
    if (l < NL - 1) {
      k_bnab<<<1, 64, 0, stream>>>(bnsum + l * 128, gamma, beta, ab + l * 64, l);
    } else {
      k_bnnorm<<<NN / 4, 256, 0, stream>>>(hout, bnsum + l * 128, gamma, beta, l);
    }
    float* t = hin; hin = hout; hout = t;
  }
  k_readout<<<NG, 256, 0, stream>>>(hin, batch, W1, b1, W2, b2, out);
}

// Round 5
// 801.056 us; speedup vs baseline: 2.5125x; 1.1771x over previous
//
#include <hip/hip_runtime.h>
#include <math.h>

#define NN 100000
#define NE 1600000
#define NG 64
#define FF 50
#define NL 3
#define NBUCK ((NN + 255) / 256)   // 391

typedef short bf16x8 __attribute__((ext_vector_type(8)));
typedef float f32x4 __attribute__((ext_vector_type(4)));

__device__ __forceinline__ short f2bf(float f) {
  return __builtin_bit_cast(short, (__bf16)f);
}
__device__ __forceinline__ float bf2f(short s) {
  unsigned int u = ((unsigned int)(unsigned short)s) << 16;
  return __builtin_bit_cast(float, u);
}

// ---------------- degree ----------------
__global__ void k_deg(const int* __restrict__ dst, int* __restrict__ deg) {
  int e = blockIdx.x * blockDim.x + threadIdx.x;
  if (e < NE) atomicAdd(&deg[dst[e]], 1);
}

// ---------------- prefix scan ----------------
__global__ void k_scan1(const int* __restrict__ deg, int* __restrict__ off, int* __restrict__ parts) {
  __shared__ int sm[1024];
  int i = blockIdx.x * 1024 + threadIdx.x;
  int v = (i < NN) ? deg[i] : 0;
  sm[threadIdx.x] = v;
  __syncthreads();
  for (int ofs = 1; ofs < 1024; ofs <<= 1) {
    int t = (threadIdx.x >= ofs) ? sm[threadIdx.x - ofs] : 0;
    __syncthreads();
    sm[threadIdx.x] += t;
    __syncthreads();
  }
  if (i < NN) off[i] = sm[threadIdx.x] - v;
  if (threadIdx.x == 1023) parts[blockIdx.x] = sm[1023];
}

__global__ void k_scan2(int* __restrict__ parts, int nb) {
  __shared__ int sm[128];
  int v = (threadIdx.x < nb) ? parts[threadIdx.x] : 0;
  sm[threadIdx.x] = v;
  __syncthreads();
  for (int ofs = 1; ofs < 128; ofs <<= 1) {
    int t = (threadIdx.x >= ofs) ? sm[threadIdx.x - ofs] : 0;
    __syncthreads();
    sm[threadIdx.x] += t;
    __syncthreads();
  }
  if (threadIdx.x < nb) parts[threadIdx.x] = sm[threadIdx.x] - v;
}

__global__ void k_scan3(int* __restrict__ off, const int* __restrict__ parts, int* __restrict__ bcur) {
  int i = blockIdx.x * 256 + threadIdx.x;
  if (i < NN) {
    int v = off[i] + parts[i >> 10];
    off[i] = v;
    if ((i & 255) == 0) bcur[i >> 8] = v;
  }
  if (i == 0) off[NN] = NE;
}

// ---------------- node init ----------------
__global__ void k_nodeinit(const int* __restrict__ deg, float* __restrict__ dinv,
                           float* __restrict__ lgc, float* __restrict__ scal) {
  int i = blockIdx.x * 256 + threadIdx.x;
  float lp = 0.f;
  if (i < NN) {
    int d = deg[i];
    dinv[i] = rsqrtf((float)(d + 1));
    int dc = d > 1 ? d : 1;
    lgc[i] = log1pf((float)dc);
    lp = log1pf((float)d);
  }
  for (int o = 32; o > 0; o >>= 1) lp += __shfl_down(lp, o);
  __shared__ float red[4];
  int lane = threadIdx.x & 63, w = threadIdx.x >> 6;
  if (lane == 0) red[w] = lp;
  __syncthreads();
  if (threadIdx.x == 0) atomicAdd(scal, red[0] + red[1] + red[2] + red[3]);
}

// ---------------- phase A: bin edges into CSR-aligned buckets ----------------
__global__ __launch_bounds__(256) void k_bucket(const int* __restrict__ src, const int* __restrict__ dst,
                                                int* __restrict__ bcur, unsigned* __restrict__ tmp) {
  __shared__ int hist[NBUCK];
  __shared__ int base[NBUCK];
  int t = threadIdx.x;
  for (int i = t; i < NBUCK; i += 256) hist[i] = 0;
  __syncthreads();
  int e0 = blockIdx.x * 4096;
  int myb[16], myrank[16];
  unsigned mypack[16];
#pragma unroll
  for (int i = 0; i < 16; ++i) {
    int e = e0 + i * 256 + t;
    if (e < NE) {
      int s = src[e], d = dst[e];
      int b = d >> 8;
      myb[i] = b;
      mypack[i] = ((unsigned)(d & 255) << 17) | (unsigned)s;
      myrank[i] = atomicAdd(&hist[b], 1);
    } else myb[i] = -1;
  }
  __syncthreads();
  for (int i = t; i < NBUCK; i += 256)
    base[i] = hist[i] ? atomicAdd(&bcur[i], hist[i]) : 0;
  __syncthreads();
#pragma unroll
  for (int i = 0; i < 16; ++i)
    if (myb[i] >= 0) tmp[base[myb[i]] + myrank[i]] = mypack[i];
}

// ---------------- phase B: sort each bucket into final CSR ----------------
__global__ __launch_bounds__(256) void k_bsort(const int* __restrict__ off, const unsigned* __restrict__ tmp,
                                               int* __restrict__ ssrc) {
  int b = blockIdx.x;
  int n0 = b * 256;
  int nEnd = n0 + 256 < NN ? n0 + 256 : NN;
  __shared__ int cnt[256];
  __shared__ int nb[256];
  int t = threadIdx.x;
  cnt[t] = 0;
  if (n0 + t < nEnd) nb[t] = off[n0 + t];
  __syncthreads();
  int lo = off[n0], hiE = off[nEnd];
  for (int e = lo + t; e < hiE; e += 256) {
    unsigned p = tmp[e];
    int dloc = p >> 17;
    int s = (int)(p & 0x1FFFFu);
    int pos = nb[dloc] + atomicAdd(&cnt[dloc], 1);
    ssrc[pos] = s;
  }
}

// ---------------- fuse post_W @ lin_W ----------------
__global__ void k_fusew(const float* __restrict__ postW, const float* __restrict__ postb,
                        const float* __restrict__ linW, const float* __restrict__ linb,
                        float* __restrict__ A, float* __restrict__ bias2) {
  int wid = (blockIdx.x * blockDim.x + threadIdx.x) >> 6;
  int f = threadIdx.x & 63;
  if (wid >= 3 * 651) return;
  int l = wid / 651, r = wid % 651;
  int fc = f < FF ? f : FF - 1;
  const float* lw = linW + l * FF * FF;
  float acc = 0.f;
  if (r < 650) {
    const float* pw = postW + (l * 650 + r) * FF;
    for (int j = 0; j < FF; ++j) acc += pw[j] * lw[j * FF + fc];
    if (f < FF) A[(l * 650 + r) * FF + f] = acc;
  } else {
    const float* pb = postb + l * FF;
    for (int j = 0; j < FF; ++j) acc += pb[j] * lw[j * FF + fc];
    if (f < FF) bias2[l * 64 + f] = acc + linb[l * FF + f];
  }
}

// ---------------- pack fused A into bf16 [l][chunk 13][col 64][k 64] ----------------
__global__ void k_packA(const float* __restrict__ Af, short* __restrict__ Abt) {
  int t = blockIdx.x * 256 + threadIdx.x;
  if (t >= 3 * 13 * 64 * 64) return;
  int kk = t & 63;
  int f = (t >> 6) & 63;
  int lc = t >> 12;
  int c = lc % 13;
  int l = lc / 13;
  float v = 0.f;
  if (kk < FF && f < FF) v = Af[((size_t)(l * 650 + c * FF + kk)) * FF + f];
  Abt[t] = f2bf(v);
}

// ---------------- pack pre_W into bf16 [l][half 2][col 64][k 64] ----------------
__global__ void k_packP(const float* __restrict__ preW, short* __restrict__ Pbt) {
  int t = blockIdx.x * 256 + threadIdx.x;
  if (t >= NL * 2 * 64 * 64) return;
  int kk = t & 63;
  int f = (t >> 6) & 63;
  int ls = t >> 12;
  int s = ls & 1, l = ls >> 1;
  float v = 0.f;
  if (kk < FF && f < FF) v = preW[(size_t)(l * 100 + s * FF + kk) * FF + f];
  Pbt[t] = f2bf(v);
}

// ---------------- GCN: p = (x @ W_gcn) * dinv  (bf16, row stride 64) ----------------
__global__ void k_gcnpre(const float* __restrict__ x, const float* __restrict__ Wg,
                         const float* __restrict__ dinv, short* __restrict__ pb) {
  int t = blockIdx.x * 256 + threadIdx.x;
  int n = t >> 6, f = t & 63;
  if (n >= NN) return;
  float v = 0.f;
  if (f < FF) v = (x[2 * n] * Wg[f] + x[2 * n + 1] * Wg[FF + f]) * dinv[n];
  pb[n * 64 + f] = f2bf(v);
}

// ---------------- GCN aggregation (wave per node, readlane broadcast) ----------------
__global__ void k_gcnagg(const short* __restrict__ pb, const int* __restrict__ off,
                         const int* __restrict__ ssrc, const float* __restrict__ dinv,
                         const float* __restrict__ bg, float* __restrict__ h) {
  int wid = (blockIdx.x * blockDim.x + threadIdx.x) >> 6;
  int lane = threadIdx.x & 63;
  if (wid >= NN) return;
  int n = wid;
  int fc = lane < FF ? lane : FF - 1;
  float acc = bf2f(pb[n * 64 + fc]);
  int lo = off[n], hi = off[n + 1];
  for (int base = lo; base < hi; base += 64) {
    int rem = hi - base;
    int cnt = rem > 64 ? 64 : rem;
    int sidx = (base + lane < hi) ? ssrc[base + lane] : 0;
    int full = cnt & ~7;
    int j = 0;
    for (; j < full; j += 8) {
#pragma unroll
      for (int i = 0; i < 8; ++i) {
        int s = __builtin_amdgcn_readlane(sidx, j + i);
        acc += bf2f(pb[s * 64 + fc]);
      }
    }
    for (; j < cnt; ++j) {
      int s = __builtin_amdgcn_readlane(sidx, j);
      acc += bf2f(pb[s * 64 + fc]);
    }
  }
  if (lane < FF) h[n * FF + lane] = dinv[n] * acc + bg[lane];
}

// ---------------- PNA pre (MFMA) ----------------
__global__ __launch_bounds__(256) void k_preM(const float* __restrict__ hin, const float2* __restrict__ ab,
                                              const short* __restrict__ Pbt, const float* __restrict__ preb,
                                              float* __restrict__ cb, short* __restrict__ bbh, int l) {
  __shared__ short Xs[128][72];
  __shared__ short Bs[2][64][72];
  int tid = threadIdx.x;
  int n0 = blockIdx.x * 128;
  int w = tid >> 6, lane = tid & 63;
  int q = lane >> 4, m16 = lane & 15;

  int bf = tid >> 2, bko = (tid & 3) * 16;
  const short* Pl = Pbt + l * 2 * 4096;
  for (int s = 0; s < 2; ++s) {
    const float4* g = (const float4*)(Pl + (s << 12) + (bf << 6) + bko);
    *(float4*)&Bs[s][bf][bko] = g[0];
    *(float4*)&Bs[s][bf][bko + 8] = g[1];
  }
  int nl = tid & 127, kh = (tid >> 7) * 32;
  int n = n0 + nl;
  bool nvalid = n < NN;
  const float* hrow = hin + (size_t)(nvalid ? n : 0) * FF;
#pragma unroll
  for (int j = 0; j < 32; j += 2) {
    int kk = kh + j;
    float2 v = {0.f, 0.f};
    if (nvalid && kk < FF) v = *(const float2*)(hrow + kk);
    if (ab) {
      float2 p0 = ab[kk], p1 = ab[kk + 1];
      v.x = fmaxf(fmaf(v.x, p0.x, p0.y), 0.f);
      v.y = fmaxf(fmaf(v.y, p1.x, p1.y), 0.f);
    }
    Xs[nl][kk] = f2bf(v.x);
    Xs[nl][kk + 1] = f2bf(v.y);
  }
  __syncthreads();

  f32x4 aT[2][4], aB2[2][4];
#pragma unroll
  for (int i = 0; i < 2; ++i)
#pragma unroll
    for (int j = 0; j < 4; ++j) {
      aT[i][j] = (f32x4){0.f, 0.f, 0.f, 0.f};
      aB2[i][j] = (f32x4){0.f, 0.f, 0.f, 0.f};
    }
#pragma unroll
  for (int hh = 0; hh < 2; ++hh) {
    int ko = hh * 32 + q * 8;
    bf16x8 a0 = *(const bf16x8*)&Xs[w * 32 + m16][ko];
    bf16x8 a1 = *(const bf16x8*)&Xs[w * 32 + 16 + m16][ko];
#pragma unroll
    for (int ft = 0; ft < 4; ++ft) {
      bf16x8 b0 = *(const bf16x8*)&Bs[0][ft * 16 + m16][ko];
      bf16x8 b1 = *(const bf16x8*)&Bs[1][ft * 16 + m16][ko];
      aT[0][ft] = __builtin_amdgcn_mfma_f32_16x16x32_bf16(a0, b0, aT[0][ft], 0, 0, 0);
      aT[1][ft] = __builtin_amdgcn_mfma_f32_16x16x32_bf16(a1, b0, aT[1][ft], 0, 0, 0);
      aB2[0][ft] = __builtin_amdgcn_mfma_f32_16x16x32_bf16(a0, b1, aB2[0][ft], 0, 0, 0);
      aB2[1][ft] = __builtin_amdgcn_mfma_f32_16x16x32_bf16(a1, b1, aB2[1][ft], 0, 0, 0);
    }
  }
#pragma unroll
  for (int mt = 0; mt < 2; ++mt) {
#pragma unroll
    for (int r = 0; r < 4; ++r) {
      int node = n0 + w * 32 + mt * 16 + q * 4 + r;
      if (node >= NN) continue;
#pragma unroll
      for (int ft = 0; ft < 4; ++ft) {
        int col = ft * 16 + m16;
        if (col < FF) cb[node * FF + col] = aT[mt][ft][r] + preb[l * FF + col];
        bbh[node * 64 + col] = f2bf(aB2[mt][ft][r]);
      }
    }
  }
}

// ---------------- PNA aggregation (wave per node, readlane, bf16 out) ----------------
__global__ void k_agg(const short* __restrict__ bbh, const float* __restrict__ cb,
                      const int* __restrict__ off, const int* __restrict__ ssrc,
                      const float* __restrict__ lgc, const float* __restrict__ scal,
                      short* __restrict__ agb, float* __restrict__ ampatt) {
  int wid = (blockIdx.x * blockDim.x + threadIdx.x) >> 6;
  int lane = threadIdx.x & 63;
  if (wid >= NN) return;
  int n = wid;
  int fc = lane < FF ? lane : FF - 1;
  float S = 0.f, S2 = 0.f, MN = INFINITY, MX = -INFINITY;
  int lo = off[n], hi = off[n + 1];
  for (int base = lo; base < hi; base += 64) {
    int rem = hi - base;
    int cnt = rem > 64 ? 64 : rem;
    int sidx = (base + lane < hi) ? ssrc[base + lane] : 0;
    int full = cnt & ~7;
    int j = 0;
    for (; j < full; j += 8) {
#pragma unroll
      for (int i = 0; i < 8; ++i) {
        int s = __builtin_amdgcn_readlane(sidx, j + i);
        float v = bf2f(bbh[s * 64 + fc]);
        S += v; S2 = fmaf(v, v, S2);
        MN = fminf(MN, v); MX = fmaxf(MX, v);
      }
    }
    for (; j < cnt; ++j) {
      int s = __builtin_amdgcn_readlane(sidx, j);
      float v = bf2f(bbh[s * 64 + fc]);
      S += v; S2 = fmaf(v, v, S2);
      MN = fminf(MN, v); MX = fmaxf(MX, v);
    }
  }
  int d = hi - lo;
  float mean, mnv, mxv, stdv;
  if (d > 0) {
    float inv = 1.f / (float)d;
    float m = S * inv;
    float var = S2 * inv - m * m; var = var > 0.f ? var : 0.f;
    stdv = sqrtf(var + 1e-5f);
    float c = cb[n * FF + fc];
    mean = c + m; mnv = c + MN; mxv = c + MX;
  } else {
    mean = 0.f; mnv = 0.f; mxv = 0.f; stdv = sqrtf(1e-5f);
  }
  short* row = agb + (size_t)n * 256;
  if (lane < FF) {
    row[lane] = f2bf(mean);
    row[64 + lane] = f2bf(mnv);
    row[128 + lane] = f2bf(mxv);
    row[192 + lane] = f2bf(stdv);
  } else {
    row[lane] = 0; row[64 + lane] = 0; row[128 + lane] = 0; row[192 + lane] = 0;
  }
  if (lane == 0) {
    float avg = scal[0] * (1.f / NN);
    float lg = lgc[n];
    ampatt[2 * n] = lg / avg;
    ampatt[2 * n + 1] = avg / lg;
  }
}

// ---------------- post GEMM (bf16 MFMA) + fused BN-stat reduction ----------------
__global__ __launch_bounds__(256) void k_gemm(const float* __restrict__ h, const float2* __restrict__ ab,
                                              const short* __restrict__ agb, const float* __restrict__ ampatt,
                                              const short* __restrict__ Abt, const float* __restrict__ bias2,
                                              float* __restrict__ out, float* __restrict__ bnsum) {
  __shared__ short Xs[128][72];
  __shared__ short Bs[3][64][72];
  __shared__ float2 redbn[4][16][16];
  int tid = threadIdx.x;
  int n0 = blockIdx.x * 128;
  int w = tid >> 6, lane = tid & 63;
  int q = lane >> 4, m16 = lane & 15;

  int nl = tid & 127;
  int kh = (tid >> 7) * 32;
  int n = n0 + nl;
  bool nvalid = n < NN;
  const float* hrow = h + (size_t)(nvalid ? n : 0) * FF;
  const short* arow = agb + (size_t)(nvalid ? n : 0) * 256;

  int bf = tid >> 2;
  int bko = (tid & 3) * 16;

  f32x4 aB[2][4], aC[2][4], aD[2][4];
#pragma unroll
  for (int i = 0; i < 2; ++i)
#pragma unroll
    for (int j = 0; j < 4; ++j) {
      aB[i][j] = (f32x4){0.f, 0.f, 0.f, 0.f};
      aC[i][j] = (f32x4){0.f, 0.f, 0.f, 0.f};
      aD[i][j] = (f32x4){0.f, 0.f, 0.f, 0.f};
    }

  for (int c = 0; c < 5; ++c) {
    if (c) __syncthreads();
    int nslice = (c == 0) ? 1 : 3;
    for (int s = 0; s < nslice; ++s) {
      int chunk = (c == 0) ? 0 : (c + 4 * s);
      const float4* g = (const float4*)(Abt + (chunk << 12) + (bf << 6) + bko);
      *(float4*)&Bs[s][bf][bko] = g[0];
      *(float4*)&Bs[s][bf][bko + 8] = g[1];
    }
    if (c == 0) {
#pragma unroll
      for (int j = 0; j < 32; j += 2) {
        int kk = kh + j;
        float2 v = {0.f, 0.f};
        if (nvalid && kk < FF) v = *(const float2*)(hrow + kk);
        if (ab) {
          float2 p0 = ab[kk], p1 = ab[kk + 1];
          v.x = fmaxf(fmaf(v.x, p0.x, p0.y), 0.f);
          v.y = fmaxf(fmaf(v.y, p1.x, p1.y), 0.f);
        }
        Xs[nl][kk] = f2bf(v.x);
        Xs[nl][kk + 1] = f2bf(v.y);
      }
    } else {
      float4 v0 = {0,0,0,0}, v1 = {0,0,0,0}, v2 = {0,0,0,0}, v3 = {0,0,0,0};
      if (nvalid) {
        const float4* g = (const float4*)(arow + (c - 1) * 64 + kh);
        v0 = g[0]; v1 = g[1]; v2 = g[2]; v3 = g[3];
      }
      float4* dstp = (float4*)&Xs[nl][kh];
      dstp[0] = v0; dstp[1] = v1; dstp[2] = v2; dstp[3] = v3;
    }
    __syncthreads();
#pragma unroll
    for (int hh = 0; hh < 2; ++hh) {
      int ko = hh * 32 + q * 8;
      bf16x8 a0 = *(const bf16x8*)&Xs[w * 32 + m16][ko];
      bf16x8 a1 = *(const bf16x8*)&Xs[w * 32 + 16 + m16][ko];
      if (c == 0) {
#pragma unroll
        for (int ft = 0; ft < 4; ++ft) {
          bf16x8 b = *(const bf16x8*)&Bs[0][ft * 16 + m16][ko];
          aB[0][ft] = __builtin_amdgcn_mfma_f32_16x16x32_bf16(a0, b, aB[0][ft], 0, 0, 0);
          aB[1][ft] = __builtin_amdgcn_mfma_f32_16x16x32_bf16(a1, b, aB[1][ft], 0, 0, 0);
        }
      } else {
#pragma unroll
        for (int ft = 0; ft < 4; ++ft) {
          bf16x8 b0 = *(const bf16x8*)&Bs[0][ft * 16 + m16][ko];
          bf16x8 b1 = *(const bf16x8*)&Bs[1][ft * 16 + m16][ko];
          bf16x8 b2 = *(const bf16x8*)&Bs[2][ft * 16 + m16][ko];
          aB[0][ft] = __builtin_amdgcn_mfma_f32_16x16x32_bf16(a0, b0, aB[0][ft], 0, 0, 0);
          aB[1][ft] = __builtin_amdgcn_mfma_f32_16x16x32_bf16(a1, b0, aB[1][ft], 0, 0, 0);
          aC[0][ft] = __builtin_amdgcn_mfma_f32_16x16x32_bf16(a0, b1, aC[0][ft], 0, 0, 0);
          aC[1][ft] = __builtin_amdgcn_mfma_f32_16x16x32_bf16(a1, b1, aC[1][ft], 0, 0, 0);
          aD[0][ft] = __builtin_amdgcn_mfma_f32_16x16x32_bf16(a0, b2, aD[0][ft], 0, 0, 0);
          aD[1][ft] = __builtin_amdgcn_mfma_f32_16x16x32_bf16(a1, b2, aD[1][ft], 0, 0, 0);
        }
      }
    }
  }
  // epilogue: write out + accumulate BN partial sums
  float sacc[4] = {0.f, 0.f, 0.f, 0.f};
  float qacc[4] = {0.f, 0.f, 0.f, 0.f};
#pragma unroll
  for (int mt = 0; mt < 2; ++mt) {
#pragma unroll
    for (int r = 0; r < 4; ++r) {
      int node = n0 + w * 32 + mt * 16 + q * 4 + r;
      if (node >= NN) continue;
      float2 aa = *(const float2*)(ampatt + 2 * node);
#pragma unroll
      for (int ft = 0; ft < 4; ++ft) {
        int col = ft * 16 + m16;
        if (col >= FF) continue;
        float val = aB[mt][ft][r] + aa.x * aC[mt][ft][r] + aa.y * aD[mt][ft][r] + bias2[col];
        out[node * FF + col] = val;
        sacc[ft] += val;
        qacc[ft] = fmaf(val, val, qacc[ft]);
      }
    }
  }
#pragma unroll
  for (int ft = 0; ft < 4; ++ft)
    redbn[ft][m16][w * 4 + q] = make_float2(sacc[ft], qacc[ft]);
  __syncthreads();
  if (tid < 64) {
    int ftl = tid >> 4, m = tid & 15;
    int col = ftl * 16 + m;
    if (col < FF) {
      float ts = 0.f, tq = 0.f;
#pragma unroll
      for (int i = 0; i < 16; ++i) {
        float2 v = redbn[ftl][m][i];
        ts += v.x; tq += v.y;
      }
      atomicAdd(&bnsum[col], ts);
      atomicAdd(&bnsum[64 + col], tq);
    }
  }
}

// ---------------- BN coeffs: a = rs*gamma, b = beta - mu*a ----------------
__global__ void k_bnab(const float* __restrict__ bnsum, const float* __restrict__ gamma,
                       const float* __restrict__ beta, float2* __restrict__ ab, int l) {
  int f = threadIdx.x;
  float a = 0.f, b = 0.f;
  if (f < FF) {
    float mu = bnsum[f] * (1.f / NN);
    float vq = bnsum[64 + f] * (1.f / NN) - mu * mu;
    float rs = rsqrtf((vq > 0.f ? vq : 0.f) + 1e-5f);
    a = rs * gamma[l * FF + f];
    b = beta[l * FF + f] - mu * a;
  }
  ab[f] = make_float2(a, b);
}

// ---------------- graph partial sums (fused BN+ReLU of last layer) ----------------
__global__ void k_gsum(const float* __restrict__ h, const float2* __restrict__ ab,
                       const int* __restrict__ batch, float* __restrict__ gsum) {
  int w = threadIdx.x >> 6, lane = threadIdx.x & 63;
  int fc = lane < FF ? lane : FF - 1;
  bool act = lane < FF;
  float2 p = ab[fc];
  int n0 = blockIdx.x * 256 + w * 64;
  if (n0 >= NN) return;
  int nEnd = n0 + 64 < NN ? n0 + 64 : NN;
  float acc = 0.f;
  int gcur = batch[n0];
  for (int n = n0; n < nEnd; ++n) {
    int g = batch[n];
    if (g != gcur) {
      if (act) atomicAdd(&gsum[gcur * 64 + lane], acc);
      acc = 0.f; gcur = g;
    }
    float v = h[n * FF + fc];
    acc += fmaxf(fmaf(v, p.x, p.y), 0.f);
  }
  if (act) atomicAdd(&gsum[gcur * 64 + lane], acc);
}

// ---------------- final MLP over 64 graphs ----------------
__global__ void k_mlp(const float* __restrict__ gsum, const float* __restrict__ W1,
                      const float* __restrict__ b1, const float* __restrict__ W2,
                      const float* __restrict__ b2, float* __restrict__ out) {
  int g = threadIdx.x;
  if (g >= NG) return;
  float gv[FF];
#pragma unroll
  for (int f = 0; f < FF; ++f) gv[f] = gsum[g * 64 + f];
  float r = b2[0];
  for (int j = 0; j < 25; ++j) {
    float a = b1[j];
#pragma unroll
    for (int f = 0; f < FF; ++f) a = fmaf(gv[f], W1[f * 25 + j], a);
    r += fmaxf(a, 0.f) * W2[j];
  }
  out[g] = r;
}

extern "C" void kernel_launch(void* const* d_in, const int* in_sizes, int n_in,
                              void* d_out, int out_size, void* d_ws, size_t ws_size,
                              hipStream_t stream) {
  const float* x     = (const float*)d_in[0];
  const int*   ei    = (const int*)d_in[1];
  const int*   src   = ei;
  const int*   dst   = ei + NE;
  const int*   batch = (const int*)d_in[2];
  const float* Wg    = (const float*)d_in[3];
  const float* bg    = (const float*)d_in[4];
  const float* preW  = (const float*)d_in[5];
  const float* preb  = (const float*)d_in[6];
  const float* postW = (const float*)d_in[7];
  const float* postb = (const float*)d_in[8];
  const float* linW  = (const float*)d_in[9];
  const float* linb  = (const float*)d_in[10];
  const float* gamma = (const float*)d_in[11];
  const float* beta  = (const float*)d_in[12];
  const float* W1    = (const float*)d_in[13];
  const float* b1    = (const float*)d_in[14];
  const float* W2    = (const float*)d_in[15];
  const float* b2    = (const float*)d_in[16];
  float* out = (float*)d_out;

  char* W = (char*)d_ws;
  int*    deg    = (int*)(W + 0);           // 400384
  int*    off    = (int*)(W + 400384);      // 400896
  int*    bcur   = (int*)(W + 801280);      // 2048
  int*    parts  = (int*)(W + 803328);      // 4096
  float*  dinv   = (float*)(W + 807424);    // 400384
  float*  lgc    = (float*)(W + 1207808);   // 400384
  float*  scal   = (float*)(W + 1608192);   // 512
  float*  bnsum  = (float*)(W + 1608704);   // 2048
  float2* ab     = (float2*)(W + 1610752);  // 1536 (3 layers x 64 float2)
  float*  Af     = (float*)(W + 1612288);   // 390144
  float*  bias2  = (float*)(W + 2002432);   // 1024
  short*  Abt    = (short*)(W + 2003456);   // 319488
  short*  Pbt    = (short*)(W + 2322944);   // 49152
  unsigned* tmp  = (unsigned*)(W + 2372096);// 6400000
  int*    ssrc   = (int*)(W + 8772096);     // 6400000
  float*  hA     = (float*)(W + 15172096);  // 20000256
  float*  hB     = (float*)(W + 35172352);  // 20000256
  float*  cb     = (float*)(W + 55172608);  // 20000256
  short*  bbh    = (short*)(W + 75172864);  // 12800256
  short*  agb    = (short*)(W + 87973120);  // 51200256
  float*  ampatt = (float*)(W + 139173376); // 800256
  float*  gsum   = (float*)(W + 139973632); // 16384  (total ~140 MB)

  hipMemsetAsync(deg, 0, 400384, stream);
  hipMemsetAsync(scal, 0, 2560, stream);    // scal + bnsum
  hipMemsetAsync(gsum, 0, 16384, stream);

  k_deg<<<(NE + 255) / 256, 256, 0, stream>>>(dst, deg);
  k_scan1<<<98, 1024, 0, stream>>>(deg, off, parts);
  k_scan2<<<1, 128, 0, stream>>>(parts, 98);
  k_scan3<<<(NN + 255) / 256, 256, 0, stream>>>(off, parts, bcur);
  k_nodeinit<<<(NN + 255) / 256, 256, 0, stream>>>(deg, dinv, lgc, scal);
  k_bucket<<<(NE + 4095) / 4096, 256, 0, stream>>>(src, dst, bcur, tmp);
  k_bsort<<<NBUCK, 256, 0, stream>>>(off, tmp, ssrc);
  k_fusew<<<(3 * 651 + 3) / 4, 256, 0, stream>>>(postW, postb, linW, linb, Af, bias2);
  k_packA<<<(3 * 13 * 64 * 64 + 255) / 256, 256, 0, stream>>>(Af, Abt);
  k_packP<<<(NL * 2 * 64 * 64 + 255) / 256, 256, 0, stream>>>(preW, Pbt);

  k_gcnpre<<<NN / 4, 256, 0, stream>>>(x, Wg, dinv, bbh);
  k_gcnagg<<<NN / 4, 256, 0, stream>>>(bbh, off, ssrc, dinv, bg, hA);

  float* hin = hA;
  float* hout = hB;
  for (int l = 0; l < NL; ++l) {
    const float2* abl = (l == 0) ? nullptr : (ab + (l - 1) * 64);
    k_preM<<<(NN + 127) / 128, 256, 0, stream>>>(hin, abl, Pbt, preb, cb, bbh, l);
    k_agg<<<NN / 4, 256, 0, stream>>>(bbh, cb, off, ssrc, lgc, scal, agb, ampatt);
    k_gemm<<<(NN + 127) / 128, 256, 0, stream>>>(hin, abl, agb, ampatt, Abt + l * 13 * 4096, bias2 + l * 64, hout, bnsum + l * 128);
    k_bnab<<<1, 64, 0, stream>>>(bnsum + l * 128, gamma, beta, ab + l * 64, l);
    float* t = hin; hin = hout; hout = t;
  }
  k_gsum<<<NBUCK, 256, 0, stream>>>(hin, ab + 2 * 64, batch, gsum);
  k_mlp<<<1, 64, 0, stream>>>(gsum, W1, b1, W2, b2, out);
}